// Round 2
// baseline (51314.917 us; speedup 1.0000x reference)
//
#include <hip/hip_runtime.h>
#include <hip/hip_bf16.h>
#include <cstdint>

// Problem constants
constexpr int kT = 128;    // sequence length
constexpr int kB = 256;    // batch
constexpr int kE = 512;    // embed dim
constexpr int kH = 1024;   // hidden
constexpr int kV = 348;    // vocab
constexpr int kNG = 3072;  // 3*H gate width
constexpr int NB = 224;    // grid size (<= 256 CUs -> all blocks resident, no coop launch needed)

typedef short s8v __attribute__((ext_vector_type(8)));   // 8 bf16 (4 VGPRs) MFMA operand
typedef float f4v __attribute__((ext_vector_type(4)));   // MFMA accumulator
typedef unsigned short u16;

__device__ __forceinline__ u16 f2bf(float x) {
  unsigned int u = __builtin_bit_cast(unsigned int, x);
  u += 0x7fffu + ((u >> 16) & 1u);          // RNE
  return (u16)(u >> 16);
}

// gate-major n = gate*H + j  ->  interleaved col = 48*(j/16) + 16*gate + (j%16)
__device__ __forceinline__ int permn(int n) {
  int gate = n >> 10, j = n & 1023;
  return ((j >> 4) * 48) + gate * 16 + (j & 15);
}

struct Params {
  const int* target; const int* bosp; const float* b_out;
  const u16 *w1i, *w1h, *w2i, *w2h, *w3i, *w3h, *wout, *embb;
  const float *bi1, *bh1, *bi2, *bh2, *bi3, *bh3;
  float *gi1, *gi2, *gi3;       // [2][B][NG] fp32 (permuted col layout)
  float *h1f, *h2f, *h3f;       // [2][B][H] fp32 state
  u16   *h1b, *h2b, *h3b;       // [2][B][H] bf16 state (matmul A operands)
  float *lp;                    // [B] output accumulator (= d_out)
  unsigned *cnt; unsigned *gen; // grid barrier state (zeroed each call)
};

union SMem {
  struct { u16 A[128 * 72]; u16 Bw[192 * 72]; } mm;  // +8 short pad per row (2-way bank alias = free)
  float logits[16 * 400];
};

// ---- hand-rolled grid barrier (device-scope; all NB blocks resident since NB <= #CUs) ----
__device__ __forceinline__ void gbar(unsigned* cnt, unsigned* gen, unsigned s) {
  __syncthreads();                          // all block's mem ops drained (vmcnt(0) before s_barrier)
  if (threadIdx.x == 0) {
    __threadfence();                        // agent-scope release of this block's writes
    unsigned a = __hip_atomic_fetch_add(cnt, 1u, __ATOMIC_ACQ_REL, __HIP_MEMORY_SCOPE_AGENT);
    if (a == (unsigned)(NB - 1)) {
      __hip_atomic_store(cnt, 0u, __ATOMIC_RELAXED, __HIP_MEMORY_SCOPE_AGENT);
      __hip_atomic_store(gen, s + 1u, __ATOMIC_RELEASE, __HIP_MEMORY_SCOPE_AGENT);
    } else {
      while (__hip_atomic_load(gen, __ATOMIC_ACQUIRE, __HIP_MEMORY_SCOPE_AGENT) <= s) {
        __builtin_amdgcn_s_sleep(2);
      }
    }
    __threadfence();                        // agent-scope acquire (invalidate L1) before consumers read
  }
  __syncthreads();
}

// ---------------- S stage: gi = A @ W^T + bias (tile 128x128, BK=64) ----------------
template<int K, bool EMB>
__device__ void do_S(SMem& sm, const u16* __restrict__ Asrc, const u16* __restrict__ Wp,
                     const float* __restrict__ biasP, float* __restrict__ giOut,
                     const int* __restrict__ target, int bos, int u, int tile)
{
  const int mt = tile / 24, nt = tile % 24;
  const int b0 = mt * 128, n0 = nt * 128;
  const int t = threadIdx.x, lane = t & 63, wv = t >> 6;
  const int wm = wv >> 1, wn = wv & 1;           // wave tile: 64 rows x 64 cols
  const int li = lane & 15, q = lane >> 4;
  f4v acc[4][4];
#pragma unroll
  for (int i = 0; i < 4; ++i)
#pragma unroll
    for (int j = 0; j < 4; ++j) acc[i][j] = f4v{0.f, 0.f, 0.f, 0.f};

  const int c8 = (t & 7) * 8, r0 = t >> 3;
  for (int k0 = 0; k0 < K; k0 += 64) {
    __syncthreads();
#pragma unroll
    for (int p = 0; p < 4; ++p) {                // A: 128 rows
      int r = r0 + 32 * p;
      const u16* src;
      if (EMB) {
        int b = b0 + r;
        int tok = (u == 0) ? bos : target[b * kT + (u - 1)];
        src = Asrc + (size_t)tok * kE;
      } else {
        src = Asrc + (size_t)(b0 + r) * K;
      }
      *(uint4*)&sm.mm.A[r * 72 + c8] = *(const uint4*)&src[k0 + c8];
    }
#pragma unroll
    for (int p = 0; p < 4; ++p) {                // B: 128 rows
      int r = r0 + 32 * p;
      *(uint4*)&sm.mm.Bw[r * 72 + c8] = *(const uint4*)&Wp[(size_t)(n0 + r) * K + k0 + c8];
    }
    __syncthreads();
#pragma unroll
    for (int kk = 0; kk < 64; kk += 32) {
      int lk = kk + q * 8;
      s8v a[4], bv[4];
#pragma unroll
      for (int m2 = 0; m2 < 4; ++m2)
        a[m2] = *(const s8v*)&sm.mm.A[(64 * wm + 16 * m2 + li) * 72 + lk];
#pragma unroll
      for (int f = 0; f < 4; ++f)
        bv[f] = *(const s8v*)&sm.mm.Bw[(64 * wn + 16 * f + li) * 72 + lk];
#pragma unroll
      for (int m2 = 0; m2 < 4; ++m2)
#pragma unroll
        for (int f = 0; f < 4; ++f)
          acc[m2][f] = __builtin_amdgcn_mfma_f32_16x16x32_bf16(a[m2], bv[f], acc[m2][f], 0, 0, 0);
    }
  }
#pragma unroll
  for (int m2 = 0; m2 < 4; ++m2)
#pragma unroll
    for (int f = 0; f < 4; ++f) {
      int n = n0 + 64 * wn + 16 * f + li;
      float bias = biasP[n];
#pragma unroll
      for (int r = 0; r < 4; ++r) {
        int b = b0 + 64 * wm + 16 * m2 + 4 * q + r;   // C/D: col=lane&15, row=(lane>>4)*4+reg
        giOut[(size_t)b * kNG + n] = acc[m2][f][r] + bias;
      }
    }
}

// ---------------- F stage: gh = h_prev @ Whh^T (tile 128x96) + fused GRU update ----------------
__device__ void do_F(SMem& sm, const u16* __restrict__ hbPrev, const float* __restrict__ hfPrev,
                     const u16* __restrict__ Whp, const float* __restrict__ bhP,
                     const float* __restrict__ giIn, float* __restrict__ hfOut,
                     u16* __restrict__ hbOut, int tile)
{
  const int mt = tile >> 5, jt = tile & 31;
  const int b0 = mt * 128, j0 = jt * 32, n0 = jt * 96;
  const int t = threadIdx.x, lane = t & 63, wv = t >> 6;
  const int wm = wv >> 1, wg = wv & 1;           // wave tile: 64 rows x 48 perm-cols (one j-group of 16)
  const int li = lane & 15, q = lane >> 4;
  f4v acc[4][3];
#pragma unroll
  for (int i = 0; i < 4; ++i)
#pragma unroll
    for (int g = 0; g < 3; ++g) acc[i][g] = f4v{0.f, 0.f, 0.f, 0.f};

  const int c8 = (t & 7) * 8, r0 = t >> 3;
  for (int k0 = 0; k0 < kH; k0 += 64) {
    __syncthreads();
#pragma unroll
    for (int p = 0; p < 4; ++p) {                // A: 128 rows
      int r = r0 + 32 * p;
      *(uint4*)&sm.mm.A[r * 72 + c8] = *(const uint4*)&hbPrev[(size_t)(b0 + r) * kH + k0 + c8];
    }
#pragma unroll
    for (int p = 0; p < 3; ++p) {                // B: 96 rows
      int r = r0 + 32 * p;
      *(uint4*)&sm.mm.Bw[r * 72 + c8] = *(const uint4*)&Whp[(size_t)(n0 + r) * kH + k0 + c8];
    }
    __syncthreads();
#pragma unroll
    for (int kk = 0; kk < 64; kk += 32) {
      int lk = kk + q * 8;
      s8v a[4], bv[3];
#pragma unroll
      for (int m2 = 0; m2 < 4; ++m2)
        a[m2] = *(const s8v*)&sm.mm.A[(64 * wm + 16 * m2 + li) * 72 + lk];
#pragma unroll
      for (int g = 0; g < 3; ++g)
        bv[g] = *(const s8v*)&sm.mm.Bw[(48 * wg + 16 * g + li) * 72 + lk];
#pragma unroll
      for (int m2 = 0; m2 < 4; ++m2)
#pragma unroll
        for (int g = 0; g < 3; ++g)
          acc[m2][g] = __builtin_amdgcn_mfma_f32_16x16x32_bf16(a[m2], bv[g], acc[m2][g], 0, 0, 0);
    }
  }
  // fused GRU update: lane-aligned r,z,n triples thanks to permuted weight layout
  {
    int j = j0 + 16 * wg + li;
    int cr = n0 + 48 * wg + li;
    float bhr = bhP[cr], bhz = bhP[cr + 16], bhn = bhP[cr + 32];
#pragma unroll
    for (int m2 = 0; m2 < 4; ++m2) {
#pragma unroll
      for (int r = 0; r < 4; ++r) {
        int b = b0 + 64 * wm + 16 * m2 + 4 * q + r;
        const float* gib = giIn + (size_t)b * kNG;
        float ghr = acc[m2][0][r] + bhr;
        float ghz = acc[m2][1][r] + bhz;
        float ghn = acc[m2][2][r] + bhn;
        float rr = gib[cr] + ghr;
        float zz = gib[cr + 16] + ghz;
        float nn = gib[cr + 32];
        float rg = 1.f / (1.f + __expf(-rr));
        float zg = 1.f / (1.f + __expf(-zz));
        float np = nn + rg * ghn;
        float nh = 2.f / (1.f + __expf(-2.f * np)) - 1.f;   // tanh
        float hold = hfPrev[(size_t)b * kH + j];
        float hnew = (1.f - zg) * nh + zg * hold;
        hfOut[(size_t)b * kH + j] = hnew;
        hbOut[(size_t)b * kH + j] = f2bf(hnew);
      }
    }
  }
}

// ---------------- E stage: logits + log_softmax + target gather (16 rows/tile) ----------------
__device__ void do_E(SMem& sm, const u16* __restrict__ h3b, const u16* __restrict__ wo,
                     const float* __restrict__ b_out, const int* __restrict__ target,
                     float* __restrict__ lp, int u, int tile)
{
  const int b0 = tile * 16;
  const int t = threadIdx.x, lane = t & 63, wv = t >> 6;
  const int li = lane & 15, q = lane >> 4;
  f4v acc[6];
#pragma unroll
  for (int f = 0; f < 6; ++f) acc[f] = f4v{0.f, 0.f, 0.f, 0.f};

  for (int k0 = 0; k0 < kH; k0 += 32) {
    int lk = k0 + q * 8;
    s8v a = *(const s8v*)&h3b[(size_t)(b0 + li) * kH + lk];
#pragma unroll
    for (int f = 0; f < 6; ++f) {
      s8v bb = *(const s8v*)&wo[(size_t)(96 * wv + 16 * f + li) * kH + lk];
      acc[f] = __builtin_amdgcn_mfma_f32_16x16x32_bf16(a, bb, acc[f], 0, 0, 0);
    }
  }
  __syncthreads();   // protect sm.logits against previous tile's softmax reads
#pragma unroll
  for (int f = 0; f < 6; ++f) {
    int n = 96 * wv + 16 * f + li;
    if (n < kV) {
      float bo = b_out[n];
#pragma unroll
      for (int r = 0; r < 4; ++r) {
        int m = 4 * q + r;
        sm.logits[m * 400 + n] = acc[f][r] + bo;
      }
    }
  }
  __syncthreads();
  int m = 4 * wv + q;
  int b = b0 + m;
  float mx = -1e30f;
  for (int cc = li; cc < kV; cc += 16) mx = fmaxf(mx, sm.logits[m * 400 + cc]);
#pragma unroll
  for (int d = 1; d < 16; d <<= 1) mx = fmaxf(mx, __shfl_xor(mx, d, 16));
  float se = 0.f;
  for (int cc = li; cc < kV; cc += 16) se += __expf(sm.logits[m * 400 + cc] - mx);
#pragma unroll
  for (int d = 1; d < 16; d <<= 1) se += __shfl_xor(se, d, 16);
  int tgt = target[b * kT + u];
  float logp = sm.logits[m * 400 + tgt] - mx - __logf(se);
  if (li == 0) lp[b] += logp;
}

// ---------------- main persistent kernel (regular launch + hand-rolled barrier) ----------------
__global__ __launch_bounds__(256, 1) void rnn_main(Params P)
{
  __shared__ SMem sm;
  const int bid = blockIdx.x;
  const int bos = P.bosp[0];
  const size_t GI = (size_t)kB * kNG, HS = (size_t)kB * kH;

  for (int s = 0; s < kT + 6; ++s) {
    if (bid < 24) {                        // S1: gi1[u]  u=s   (24 blocks x 2 tiles, 48 tiles K=512)
      int u = s;
      if (u < kT)
        for (int tt = 0; tt < 2; ++tt)
          do_S<kE, true>(sm, P.embb, P.w1i, P.bi1, P.gi1 + (size_t)(u & 1) * GI,
                         P.target, bos, u, bid * 2 + tt);
    } else if (bid < 56) {                 // F1: h1[u]  u=s-1  (32 blocks x 2 tiles, 64 tiles)
      int u = s - 1;
      if (u >= 0 && u < kT)
        for (int tt = 0; tt < 2; ++tt)
          do_F(sm, P.h1b + (size_t)((u - 1) & 1) * HS, P.h1f + (size_t)((u - 1) & 1) * HS,
               P.w1h, P.bh1, P.gi1 + (size_t)(u & 1) * GI,
               P.h1f + (size_t)(u & 1) * HS, P.h1b + (size_t)(u & 1) * HS, (bid - 24) * 2 + tt);
    } else if (bid < 104) {                // S2: gi2[u]  u=s-2 (48 blocks x 1 tile)
      int u = s - 2;
      if (u >= 0 && u < kT)
        do_S<kH, false>(sm, P.h1b + (size_t)(u & 1) * HS, P.w2i, P.bi2,
                        P.gi2 + (size_t)(u & 1) * GI, P.target, bos, u, bid - 56);
    } else if (bid < 136) {                // F2: h2[u]  u=s-3
      int u = s - 3;
      if (u >= 0 && u < kT)
        for (int tt = 0; tt < 2; ++tt)
          do_F(sm, P.h2b + (size_t)((u - 1) & 1) * HS, P.h2f + (size_t)((u - 1) & 1) * HS,
               P.w2h, P.bh2, P.gi2 + (size_t)(u & 1) * GI,
               P.h2f + (size_t)(u & 1) * HS, P.h2b + (size_t)(u & 1) * HS, (bid - 104) * 2 + tt);
    } else if (bid < 184) {                // S3: gi3[u]  u=s-4
      int u = s - 4;
      if (u >= 0 && u < kT)
        do_S<kH, false>(sm, P.h2b + (size_t)(u & 1) * HS, P.w3i, P.bi3,
                        P.gi3 + (size_t)(u & 1) * GI, P.target, bos, u, bid - 136);
    } else if (bid < 216) {                // F3: h3[u]  u=s-5
      int u = s - 5;
      if (u >= 0 && u < kT)
        for (int tt = 0; tt < 2; ++tt)
          do_F(sm, P.h3b + (size_t)((u - 1) & 1) * HS, P.h3f + (size_t)((u - 1) & 1) * HS,
               P.w3h, P.bh3, P.gi3 + (size_t)(u & 1) * GI,
               P.h3f + (size_t)(u & 1) * HS, P.h3b + (size_t)(u & 1) * HS, (bid - 184) * 2 + tt);
    } else {                               // E: logits/logsoftmax  u=s-6 (8 blocks x 2 tiles)
      int u = s - 6;
      if (u >= 0 && u < kT)
        for (int tt = 0; tt < 2; ++tt)
          do_E(sm, P.h3b + (size_t)(u & 1) * HS, P.wout, P.b_out, P.target, P.lp, u,
               (bid - 216) * 2 + tt);
    }
    gbar(P.cnt, P.gen, (unsigned)s);
  }
}

// ---------------- conversion / init kernels ----------------
__global__ void k_conv_w(const float* __restrict__ w, u16* __restrict__ wp, int K, int logK) {
  int idx = blockIdx.x * 256 + threadIdx.x;
  if (idx >= kNG * K) return;
  int n = idx >> logK, k = idx & (K - 1);
  wp[(size_t)permn(n) * K + k] = f2bf(w[idx]);
}
__global__ void k_conv_b(const float* __restrict__ b, float* __restrict__ bp) {
  int idx = blockIdx.x * 256 + threadIdx.x;
  if (idx < kNG) bp[permn(idx)] = b[idx];
}
__global__ void k_conv_wout(const float* __restrict__ w, u16* __restrict__ wp) {
  int idx = blockIdx.x * 256 + threadIdx.x;
  if (idx >= 384 * kH) return;
  int n = idx >> 10, k = idx & 1023;
  wp[idx] = (n < kV) ? f2bf(w[(size_t)n * kH + k]) : (u16)0;
}
__global__ void k_conv_emb(const float* __restrict__ e, u16* __restrict__ ep) {
  int idx = blockIdx.x * 256 + threadIdx.x;
  if (idx < kV * kE) ep[idx] = f2bf(e[idx]);
}

extern "C" void kernel_launch(void* const* d_in, const int* in_sizes, int n_in,
                              void* d_out, int out_size, void* d_ws, size_t ws_size,
                              hipStream_t stream)
{
  const int*   target = (const int*)d_in[0];
  const int*   bosp   = (const int*)d_in[1];
  const float* emb    = (const float*)d_in[2];
  const float* w_ih1  = (const float*)d_in[3];
  const float* w_hh1  = (const float*)d_in[4];
  const float* b_ih1  = (const float*)d_in[5];
  const float* b_hh1  = (const float*)d_in[6];
  const float* w_ih2  = (const float*)d_in[7];
  const float* w_hh2  = (const float*)d_in[8];
  const float* b_ih2  = (const float*)d_in[9];
  const float* b_hh2  = (const float*)d_in[10];
  const float* w_ih3  = (const float*)d_in[11];
  const float* w_hh3  = (const float*)d_in[12];
  const float* b_ih3  = (const float*)d_in[13];
  const float* b_hh3  = (const float*)d_in[14];
  const float* w_out  = (const float*)d_in[15];
  const float* b_out  = (const float*)d_in[16];

  char* ws = (char*)d_ws;
  size_t off = 0;
  auto alloc = [&](size_t bytes) -> void* {
    void* p = ws + off;
    off = (off + bytes + 511) & ~(size_t)511;
    return p;
  };
  u16* w1i = (u16*)alloc((size_t)kNG * kE * 2);
  u16* w1h = (u16*)alloc((size_t)kNG * kH * 2);
  u16* w2i = (u16*)alloc((size_t)kNG * kH * 2);
  u16* w2h = (u16*)alloc((size_t)kNG * kH * 2);
  u16* w3i = (u16*)alloc((size_t)kNG * kH * 2);
  u16* w3h = (u16*)alloc((size_t)kNG * kH * 2);
  u16* wo  = (u16*)alloc((size_t)384 * kH * 2);
  u16* eb  = (u16*)alloc((size_t)kV * kE * 2);
  float* bi1 = (float*)alloc(kNG * 4);
  float* bh1 = (float*)alloc(kNG * 4);
  float* bi2 = (float*)alloc(kNG * 4);
  float* bh2 = (float*)alloc(kNG * 4);
  float* bi3 = (float*)alloc(kNG * 4);
  float* bh3 = (float*)alloc(kNG * 4);
  float* gi1 = (float*)alloc((size_t)2 * kB * kNG * 4);
  float* gi2 = (float*)alloc((size_t)2 * kB * kNG * 4);
  float* gi3 = (float*)alloc((size_t)2 * kB * kNG * 4);
  float* h1f = (float*)alloc((size_t)2 * kB * kH * 4);
  float* h2f = (float*)alloc((size_t)2 * kB * kH * 4);
  float* h3f = (float*)alloc((size_t)2 * kB * kH * 4);
  u16* h1b = (u16*)alloc((size_t)2 * kB * kH * 2);
  u16* h2b = (u16*)alloc((size_t)2 * kB * kH * 2);
  u16* h3b = (u16*)alloc((size_t)2 * kB * kH * 2);
  unsigned* bar = (unsigned*)alloc(512);
  (void)ws_size; (void)in_sizes; (void)n_in; (void)out_size;

  // weight/bias/embedding conversion (runs every call)
  k_conv_w<<<(kNG * kE + 255) / 256, 256, 0, stream>>>(w_ih1, w1i, kE, 9);
  k_conv_w<<<(kNG * kH + 255) / 256, 256, 0, stream>>>(w_hh1, w1h, kH, 10);
  k_conv_w<<<(kNG * kH + 255) / 256, 256, 0, stream>>>(w_ih2, w2i, kH, 10);
  k_conv_w<<<(kNG * kH + 255) / 256, 256, 0, stream>>>(w_hh2, w2h, kH, 10);
  k_conv_w<<<(kNG * kH + 255) / 256, 256, 0, stream>>>(w_ih3, w3i, kH, 10);
  k_conv_w<<<(kNG * kH + 255) / 256, 256, 0, stream>>>(w_hh3, w3h, kH, 10);
  k_conv_b<<<(kNG + 255) / 256, 256, 0, stream>>>(b_ih1, bi1);
  k_conv_b<<<(kNG + 255) / 256, 256, 0, stream>>>(b_hh1, bh1);
  k_conv_b<<<(kNG + 255) / 256, 256, 0, stream>>>(b_ih2, bi2);
  k_conv_b<<<(kNG + 255) / 256, 256, 0, stream>>>(b_hh2, bh2);
  k_conv_b<<<(kNG + 255) / 256, 256, 0, stream>>>(b_ih3, bi3);
  k_conv_b<<<(kNG + 255) / 256, 256, 0, stream>>>(b_hh3, bh3);
  k_conv_wout<<<(384 * kH + 255) / 256, 256, 0, stream>>>(w_out, wo);
  k_conv_emb<<<(kV * kE + 255) / 256, 256, 0, stream>>>(emb, eb);

  // zero hidden state rings + barrier + output accumulator (ws/d_out are poisoned 0xAA)
  hipMemsetAsync(h1f, 0, (size_t)3 * 2 * kB * kH * 4, stream);  // h1f,h2f,h3f contiguous
  hipMemsetAsync(h1b, 0, (size_t)3 * 2 * kB * kH * 2, stream);  // h1b,h2b,h3b contiguous
  hipMemsetAsync(bar, 0, 512, stream);
  hipMemsetAsync(d_out, 0, (size_t)kB * 4, stream);

  Params P;
  P.target = target; P.bosp = bosp; P.b_out = b_out;
  P.w1i = w1i; P.w1h = w1h; P.w2i = w2i; P.w2h = w2h; P.w3i = w3i; P.w3h = w3h;
  P.wout = wo; P.embb = eb;
  P.bi1 = bi1; P.bh1 = bh1; P.bi2 = bi2; P.bh2 = bh2; P.bi3 = bi3; P.bh3 = bh3;
  P.gi1 = gi1; P.gi2 = gi2; P.gi3 = gi3;
  P.h1f = h1f; P.h2f = h2f; P.h3f = h3f;
  P.h1b = h1b; P.h2b = h2b; P.h3b = h3b;
  P.lp = (float*)d_out;
  P.cnt = bar; P.gen = bar + 64;   // separate cachelines

  rnn_main<<<dim3(NB), dim3(256), 0, stream>>>(P);
}

// Round 3
// 14052.820 us; speedup vs baseline: 3.6516x; 3.6516x over previous
//
#include <hip/hip_runtime.h>
#include <hip/hip_bf16.h>
#include <cstdint>

// Problem constants
constexpr int kT = 128;    // sequence length
constexpr int kB = 256;    // batch
constexpr int kE = 512;    // embed dim
constexpr int kH = 1024;   // hidden
constexpr int kV = 348;    // vocab
constexpr int kNG = 3072;  // 3*H gate width
constexpr int NB = 224;    // grid size (<= 256 CUs -> all blocks resident)

typedef short s8v __attribute__((ext_vector_type(8)));   // 8 bf16 (4 VGPRs) MFMA operand
typedef float f4v __attribute__((ext_vector_type(4)));   // MFMA accumulator
typedef unsigned short u16;

__device__ __forceinline__ u16 f2bf(float x) {
  unsigned int u = __builtin_bit_cast(unsigned int, x);
  u += 0x7fffu + ((u >> 16) & 1u);          // RNE
  return (u16)(u >> 16);
}

// gate-major n = gate*H + j  ->  interleaved col = 48*(j/16) + 16*gate + (j%16)
__device__ __forceinline__ int permn(int n) {
  int gate = n >> 10, j = n & 1023;
  return ((j >> 4) * 48) + gate * 16 + (j & 15);
}

struct Params {
  const int* target; const int* bosp; const float* b_out;
  const u16 *w1i, *w1h, *w2i, *w2h, *w3i, *w3h, *wout, *embb;
  const float *bi1, *bh1, *bi2, *bh2, *bi3, *bh3;
  float *gi1, *gi2, *gi3;       // [2][B][NG] fp32 (permuted col layout)
  float *h1f, *h2f, *h3f;       // [2][B][H] fp32 state
  u16   *h1b, *h2b, *h3b;       // [2][B][H] bf16 state (matmul A operands)
  float *lp;                    // [B] output accumulator (= d_out)
  unsigned *acnt; unsigned *gflag; // grid barrier state (zeroed each call)
};

union SMem {
  struct { u16 A[128 * 72]; u16 Bw[192 * 72]; } mm;  // +8 short pad per row
  float logits[16 * 400];
};

// ---- grid barrier v2: RELAXED flag ops (no per-poll buffer_inv), one release +
// one acquire fence per block per slot. 8 arrival lines (monotonic, no reset),
// block 0 gathers and publishes to 8 replicated go-flags. ----
__device__ __forceinline__ void gbar(unsigned* acnt, unsigned* gflag, unsigned s) {
  __syncthreads();                          // drain block's mem ops
  if (threadIdx.x == 0) {
    __threadfence();                        // agent release: dirty lines -> coherent point
    const unsigned g = blockIdx.x & 7u;
    __hip_atomic_fetch_add(&acnt[g * 16], 1u, __ATOMIC_RELAXED, __HIP_MEMORY_SCOPE_AGENT);
    if (blockIdx.x == 0) {
      for (;;) {
        unsigned sum = 0;
#pragma unroll
        for (int i = 0; i < 8; ++i)
          sum += __hip_atomic_load(&acnt[i * 16], __ATOMIC_RELAXED, __HIP_MEMORY_SCOPE_AGENT);
        if (sum >= (unsigned)NB * (s + 1u)) break;
        __builtin_amdgcn_s_sleep(2);
      }
#pragma unroll
      for (int i = 0; i < 8; ++i)
        __hip_atomic_store(&gflag[i * 16], s + 1u, __ATOMIC_RELAXED, __HIP_MEMORY_SCOPE_AGENT);
    } else {
      while (__hip_atomic_load(&gflag[g * 16], __ATOMIC_RELAXED, __HIP_MEMORY_SCOPE_AGENT) <= s)
        __builtin_amdgcn_s_sleep(16);
    }
    __threadfence();                        // agent acquire: invalidate L1/L2 once before reads
  }
  __syncthreads();
}

// ---------------- S stage: gi = A @ W^T + bias (tile 128x128, BK=64) ----------------
template<int K, bool EMB>
__device__ void do_S(SMem& sm, const u16* __restrict__ Asrc, const u16* __restrict__ Wp,
                     const float* __restrict__ biasP, float* __restrict__ giOut,
                     const int* __restrict__ target, int bos, int u, int tile)
{
  const int mt = tile / 24, nt = tile % 24;
  const int b0 = mt * 128, n0 = nt * 128;
  const int t = threadIdx.x, lane = t & 63, wv = t >> 6;
  const int wm = wv >> 1, wn = wv & 1;           // wave tile: 64 rows x 64 cols
  const int li = lane & 15, q = lane >> 4;
  f4v acc[4][4];
#pragma unroll
  for (int i = 0; i < 4; ++i)
#pragma unroll
    for (int j = 0; j < 4; ++j) acc[i][j] = f4v{0.f, 0.f, 0.f, 0.f};

  const int c8 = (t & 7) * 8, r0 = t >> 3;
  for (int k0 = 0; k0 < K; k0 += 64) {
    __syncthreads();
#pragma unroll
    for (int p = 0; p < 4; ++p) {                // A: 128 rows
      int r = r0 + 32 * p;
      const u16* src;
      if (EMB) {
        int b = b0 + r;
        int tok = (u == 0) ? bos : target[b * kT + (u - 1)];
        src = Asrc + (size_t)tok * kE;
      } else {
        src = Asrc + (size_t)(b0 + r) * K;
      }
      *(uint4*)&sm.mm.A[r * 72 + c8] = *(const uint4*)&src[k0 + c8];
    }
#pragma unroll
    for (int p = 0; p < 4; ++p) {                // B: 128 rows
      int r = r0 + 32 * p;
      *(uint4*)&sm.mm.Bw[r * 72 + c8] = *(const uint4*)&Wp[(size_t)(n0 + r) * K + k0 + c8];
    }
    __syncthreads();
#pragma unroll
    for (int kk = 0; kk < 64; kk += 32) {
      int lk = kk + q * 8;
      s8v a[4], bv[4];
#pragma unroll
      for (int m2 = 0; m2 < 4; ++m2)
        a[m2] = *(const s8v*)&sm.mm.A[(64 * wm + 16 * m2 + li) * 72 + lk];
#pragma unroll
      for (int f = 0; f < 4; ++f)
        bv[f] = *(const s8v*)&sm.mm.Bw[(64 * wn + 16 * f + li) * 72 + lk];
#pragma unroll
      for (int m2 = 0; m2 < 4; ++m2)
#pragma unroll
        for (int f = 0; f < 4; ++f)
          acc[m2][f] = __builtin_amdgcn_mfma_f32_16x16x32_bf16(a[m2], bv[f], acc[m2][f], 0, 0, 0);
    }
  }
#pragma unroll
  for (int m2 = 0; m2 < 4; ++m2)
#pragma unroll
    for (int f = 0; f < 4; ++f) {
      int n = n0 + 64 * wn + 16 * f + li;
      float bias = biasP[n];
#pragma unroll
      for (int r = 0; r < 4; ++r) {
        int b = b0 + 64 * wm + 16 * m2 + 4 * q + r;   // C/D: col=lane&15, row=(lane>>4)*4+reg
        giOut[(size_t)b * kNG + n] = acc[m2][f][r] + bias;
      }
    }
}

// ---------------- F stage: gh = h_prev @ Whh^T (tile 128x96) + fused GRU update ----------------
__device__ void do_F(SMem& sm, const u16* __restrict__ hbPrev, const float* __restrict__ hfPrev,
                     const u16* __restrict__ Whp, const float* __restrict__ bhP,
                     const float* __restrict__ giIn, float* __restrict__ hfOut,
                     u16* __restrict__ hbOut, int tile)
{
  const int mt = tile >> 5, jt = tile & 31;
  const int b0 = mt * 128, j0 = jt * 32, n0 = jt * 96;
  const int t = threadIdx.x, lane = t & 63, wv = t >> 6;
  const int wm = wv >> 1, wg = wv & 1;           // wave tile: 64 rows x 48 perm-cols
  const int li = lane & 15, q = lane >> 4;
  f4v acc[4][3];
#pragma unroll
  for (int i = 0; i < 4; ++i)
#pragma unroll
    for (int g = 0; g < 3; ++g) acc[i][g] = f4v{0.f, 0.f, 0.f, 0.f};

  const int c8 = (t & 7) * 8, r0 = t >> 3;
  for (int k0 = 0; k0 < kH; k0 += 64) {
    __syncthreads();
#pragma unroll
    for (int p = 0; p < 4; ++p) {                // A: 128 rows
      int r = r0 + 32 * p;
      *(uint4*)&sm.mm.A[r * 72 + c8] = *(const uint4*)&hbPrev[(size_t)(b0 + r) * kH + k0 + c8];
    }
#pragma unroll
    for (int p = 0; p < 3; ++p) {                // B: 96 rows
      int r = r0 + 32 * p;
      *(uint4*)&sm.mm.Bw[r * 72 + c8] = *(const uint4*)&Whp[(size_t)(n0 + r) * kH + k0 + c8];
    }
    __syncthreads();
#pragma unroll
    for (int kk = 0; kk < 64; kk += 32) {
      int lk = kk + q * 8;
      s8v a[4], bv[3];
#pragma unroll
      for (int m2 = 0; m2 < 4; ++m2)
        a[m2] = *(const s8v*)&sm.mm.A[(64 * wm + 16 * m2 + li) * 72 + lk];
#pragma unroll
      for (int g = 0; g < 3; ++g)
        bv[g] = *(const s8v*)&sm.mm.Bw[(48 * wg + 16 * g + li) * 72 + lk];
#pragma unroll
      for (int m2 = 0; m2 < 4; ++m2)
#pragma unroll
        for (int g = 0; g < 3; ++g)
          acc[m2][g] = __builtin_amdgcn_mfma_f32_16x16x32_bf16(a[m2], bv[g], acc[m2][g], 0, 0, 0);
    }
  }
  // fused GRU update: lane-aligned r,z,n triples thanks to permuted weight layout
  {
    int j = j0 + 16 * wg + li;
    int cr = n0 + 48 * wg + li;
    float bhr = bhP[cr], bhz = bhP[cr + 16], bhn = bhP[cr + 32];
#pragma unroll
    for (int m2 = 0; m2 < 4; ++m2) {
#pragma unroll
      for (int r = 0; r < 4; ++r) {
        int b = b0 + 64 * wm + 16 * m2 + 4 * q + r;
        const float* gib = giIn + (size_t)b * kNG;
        float ghr = acc[m2][0][r] + bhr;
        float ghz = acc[m2][1][r] + bhz;
        float ghn = acc[m2][2][r] + bhn;
        float rr = gib[cr] + ghr;
        float zz = gib[cr + 16] + ghz;
        float nn = gib[cr + 32];
        float rg = 1.f / (1.f + __expf(-rr));
        float zg = 1.f / (1.f + __expf(-zz));
        float np = nn + rg * ghn;
        float nh = 2.f / (1.f + __expf(-2.f * np)) - 1.f;   // tanh
        float hold = hfPrev[(size_t)b * kH + j];
        float hnew = (1.f - zg) * nh + zg * hold;
        hfOut[(size_t)b * kH + j] = hnew;
        hbOut[(size_t)b * kH + j] = f2bf(hnew);
      }
    }
  }
}

// ---------------- E stage: logits + log_softmax + target gather (16 rows/tile) ----------------
__device__ void do_E(SMem& sm, const u16* __restrict__ h3b, const u16* __restrict__ wo,
                     const float* __restrict__ b_out, const int* __restrict__ target,
                     float* __restrict__ lp, int u, int tile)
{
  const int b0 = tile * 16;
  const int t = threadIdx.x, lane = t & 63, wv = t >> 6;
  const int li = lane & 15, q = lane >> 4;
  f4v acc[6];
#pragma unroll
  for (int f = 0; f < 6; ++f) acc[f] = f4v{0.f, 0.f, 0.f, 0.f};

  for (int k0 = 0; k0 < kH; k0 += 32) {
    int lk = k0 + q * 8;
    s8v a = *(const s8v*)&h3b[(size_t)(b0 + li) * kH + lk];
#pragma unroll
    for (int f = 0; f < 6; ++f) {
      s8v bb = *(const s8v*)&wo[(size_t)(96 * wv + 16 * f + li) * kH + lk];
      acc[f] = __builtin_amdgcn_mfma_f32_16x16x32_bf16(a, bb, acc[f], 0, 0, 0);
    }
  }
  __syncthreads();   // protect sm.logits against previous tile's softmax reads
#pragma unroll
  for (int f = 0; f < 6; ++f) {
    int n = 96 * wv + 16 * f + li;
    if (n < kV) {
      float bo = b_out[n];
#pragma unroll
      for (int r = 0; r < 4; ++r) {
        int m = 4 * q + r;
        sm.logits[m * 400 + n] = acc[f][r] + bo;
      }
    }
  }
  __syncthreads();
  int m = 4 * wv + q;
  int b = b0 + m;
  float mx = -1e30f;
  for (int cc = li; cc < kV; cc += 16) mx = fmaxf(mx, sm.logits[m * 400 + cc]);
#pragma unroll
  for (int d = 1; d < 16; d <<= 1) mx = fmaxf(mx, __shfl_xor(mx, d, 16));
  float se = 0.f;
  for (int cc = li; cc < kV; cc += 16) se += __expf(sm.logits[m * 400 + cc] - mx);
#pragma unroll
  for (int d = 1; d < 16; d <<= 1) se += __shfl_xor(se, d, 16);
  int tgt = target[b * kT + u];
  float logp = sm.logits[m * 400 + tgt] - mx - __logf(se);
  if (li == 0) lp[b] += logp;
}

// ---------------- main persistent kernel ----------------
__global__ __launch_bounds__(256, 1) void rnn_main(Params P)
{
  __shared__ SMem sm;
  const int bid = blockIdx.x;
  const int bos = P.bosp[0];
  const size_t GI = (size_t)kB * kNG, HS = (size_t)kB * kH;

  for (int s = 0; s < kT + 6; ++s) {
    if (bid < 24) {                        // S1: gi1[u]  u=s   (24 blocks x 2 tiles)
      int u = s;
      if (u < kT)
        for (int tt = 0; tt < 2; ++tt)
          do_S<kE, true>(sm, P.embb, P.w1i, P.bi1, P.gi1 + (size_t)(u & 1) * GI,
                         P.target, bos, u, bid * 2 + tt);
    } else if (bid < 56) {                 // F1: h1[u]  u=s-1  (32 blocks x 2 tiles)
      int u = s - 1;
      if (u >= 0 && u < kT)
        for (int tt = 0; tt < 2; ++tt)
          do_F(sm, P.h1b + (size_t)((u - 1) & 1) * HS, P.h1f + (size_t)((u - 1) & 1) * HS,
               P.w1h, P.bh1, P.gi1 + (size_t)(u & 1) * GI,
               P.h1f + (size_t)(u & 1) * HS, P.h1b + (size_t)(u & 1) * HS, (bid - 24) * 2 + tt);
    } else if (bid < 104) {                // S2: gi2[u]  u=s-2 (48 blocks x 1 tile)
      int u = s - 2;
      if (u >= 0 && u < kT)
        do_S<kH, false>(sm, P.h1b + (size_t)(u & 1) * HS, P.w2i, P.bi2,
                        P.gi2 + (size_t)(u & 1) * GI, P.target, bos, u, bid - 56);
    } else if (bid < 136) {                // F2: h2[u]  u=s-3
      int u = s - 3;
      if (u >= 0 && u < kT)
        for (int tt = 0; tt < 2; ++tt)
          do_F(sm, P.h2b + (size_t)((u - 1) & 1) * HS, P.h2f + (size_t)((u - 1) & 1) * HS,
               P.w2h, P.bh2, P.gi2 + (size_t)(u & 1) * GI,
               P.h2f + (size_t)(u & 1) * HS, P.h2b + (size_t)(u & 1) * HS, (bid - 104) * 2 + tt);
    } else if (bid < 184) {                // S3: gi3[u]  u=s-4
      int u = s - 4;
      if (u >= 0 && u < kT)
        do_S<kH, false>(sm, P.h2b + (size_t)(u & 1) * HS, P.w3i, P.bi3,
                        P.gi3 + (size_t)(u & 1) * GI, P.target, bos, u, bid - 136);
    } else if (bid < 216) {                // F3: h3[u]  u=s-5
      int u = s - 5;
      if (u >= 0 && u < kT)
        for (int tt = 0; tt < 2; ++tt)
          do_F(sm, P.h3b + (size_t)((u - 1) & 1) * HS, P.h3f + (size_t)((u - 1) & 1) * HS,
               P.w3h, P.bh3, P.gi3 + (size_t)(u & 1) * GI,
               P.h3f + (size_t)(u & 1) * HS, P.h3b + (size_t)(u & 1) * HS, (bid - 184) * 2 + tt);
    } else {                               // E: logits/logsoftmax  u=s-6 (8 blocks x 2 tiles)
      int u = s - 6;
      if (u >= 0 && u < kT)
        for (int tt = 0; tt < 2; ++tt)
          do_E(sm, P.h3b + (size_t)(u & 1) * HS, P.wout, P.b_out, P.target, P.lp, u,
               (bid - 216) * 2 + tt);
    }
    gbar(P.acnt, P.gflag, (unsigned)s);
  }
}

// ---------------- conversion / init kernels ----------------
__global__ void k_conv_w(const float* __restrict__ w, u16* __restrict__ wp, int K, int logK) {
  int idx = blockIdx.x * 256 + threadIdx.x;
  if (idx >= kNG * K) return;
  int n = idx >> logK, k = idx & (K - 1);
  wp[(size_t)permn(n) * K + k] = f2bf(w[idx]);
}
__global__ void k_conv_b(const float* __restrict__ b, float* __restrict__ bp) {
  int idx = blockIdx.x * 256 + threadIdx.x;
  if (idx < kNG) bp[permn(idx)] = b[idx];
}
__global__ void k_conv_wout(const float* __restrict__ w, u16* __restrict__ wp) {
  int idx = blockIdx.x * 256 + threadIdx.x;
  if (idx >= 384 * kH) return;
  int n = idx >> 10, k = idx & 1023;
  wp[idx] = (n < kV) ? f2bf(w[(size_t)n * kH + k]) : (u16)0;
}
__global__ void k_conv_emb(const float* __restrict__ e, u16* __restrict__ ep) {
  int idx = blockIdx.x * 256 + threadIdx.x;
  if (idx < kV * kE) ep[idx] = f2bf(e[idx]);
}

extern "C" void kernel_launch(void* const* d_in, const int* in_sizes, int n_in,
                              void* d_out, int out_size, void* d_ws, size_t ws_size,
                              hipStream_t stream)
{
  const int*   target = (const int*)d_in[0];
  const int*   bosp   = (const int*)d_in[1];
  const float* emb    = (const float*)d_in[2];
  const float* w_ih1  = (const float*)d_in[3];
  const float* w_hh1  = (const float*)d_in[4];
  const float* b_ih1  = (const float*)d_in[5];
  const float* b_hh1  = (const float*)d_in[6];
  const float* w_ih2  = (const float*)d_in[7];
  const float* w_hh2  = (const float*)d_in[8];
  const float* b_ih2  = (const float*)d_in[9];
  const float* b_hh2  = (const float*)d_in[10];
  const float* w_ih3  = (const float*)d_in[11];
  const float* w_hh3  = (const float*)d_in[12];
  const float* b_ih3  = (const float*)d_in[13];
  const float* b_hh3  = (const float*)d_in[14];
  const float* w_out  = (const float*)d_in[15];
  const float* b_out  = (const float*)d_in[16];

  char* ws = (char*)d_ws;
  size_t off = 0;
  auto alloc = [&](size_t bytes) -> void* {
    void* p = ws + off;
    off = (off + bytes + 511) & ~(size_t)511;
    return p;
  };
  u16* w1i = (u16*)alloc((size_t)kNG * kE * 2);
  u16* w1h = (u16*)alloc((size_t)kNG * kH * 2);
  u16* w2i = (u16*)alloc((size_t)kNG * kH * 2);
  u16* w2h = (u16*)alloc((size_t)kNG * kH * 2);
  u16* w3i = (u16*)alloc((size_t)kNG * kH * 2);
  u16* w3h = (u16*)alloc((size_t)kNG * kH * 2);
  u16* wo  = (u16*)alloc((size_t)384 * kH * 2);
  u16* eb  = (u16*)alloc((size_t)kV * kE * 2);
  float* bi1 = (float*)alloc(kNG * 4);
  float* bh1 = (float*)alloc(kNG * 4);
  float* bi2 = (float*)alloc(kNG * 4);
  float* bh2 = (float*)alloc(kNG * 4);
  float* bi3 = (float*)alloc(kNG * 4);
  float* bh3 = (float*)alloc(kNG * 4);
  float* gi1 = (float*)alloc((size_t)2 * kB * kNG * 4);
  float* gi2 = (float*)alloc((size_t)2 * kB * kNG * 4);
  float* gi3 = (float*)alloc((size_t)2 * kB * kNG * 4);
  float* h1f = (float*)alloc((size_t)2 * kB * kH * 4);
  float* h2f = (float*)alloc((size_t)2 * kB * kH * 4);
  float* h3f = (float*)alloc((size_t)2 * kB * kH * 4);
  u16* h1b = (u16*)alloc((size_t)2 * kB * kH * 2);
  u16* h2b = (u16*)alloc((size_t)2 * kB * kH * 2);
  u16* h3b = (u16*)alloc((size_t)2 * kB * kH * 2);
  unsigned* bar = (unsigned*)alloc(1024);
  (void)ws_size; (void)in_sizes; (void)n_in; (void)out_size;

  // weight/bias/embedding conversion (runs every call)
  k_conv_w<<<(kNG * kE + 255) / 256, 256, 0, stream>>>(w_ih1, w1i, kE, 9);
  k_conv_w<<<(kNG * kH + 255) / 256, 256, 0, stream>>>(w_hh1, w1h, kH, 10);
  k_conv_w<<<(kNG * kH + 255) / 256, 256, 0, stream>>>(w_ih2, w2i, kH, 10);
  k_conv_w<<<(kNG * kH + 255) / 256, 256, 0, stream>>>(w_hh2, w2h, kH, 10);
  k_conv_w<<<(kNG * kH + 255) / 256, 256, 0, stream>>>(w_ih3, w3i, kH, 10);
  k_conv_w<<<(kNG * kH + 255) / 256, 256, 0, stream>>>(w_hh3, w3h, kH, 10);
  k_conv_b<<<(kNG + 255) / 256, 256, 0, stream>>>(b_ih1, bi1);
  k_conv_b<<<(kNG + 255) / 256, 256, 0, stream>>>(b_hh1, bh1);
  k_conv_b<<<(kNG + 255) / 256, 256, 0, stream>>>(b_ih2, bi2);
  k_conv_b<<<(kNG + 255) / 256, 256, 0, stream>>>(b_hh2, bh2);
  k_conv_b<<<(kNG + 255) / 256, 256, 0, stream>>>(b_ih3, bi3);
  k_conv_b<<<(kNG + 255) / 256, 256, 0, stream>>>(b_hh3, bh3);
  k_conv_wout<<<(384 * kH + 255) / 256, 256, 0, stream>>>(w_out, wo);
  k_conv_emb<<<(kV * kE + 255) / 256, 256, 0, stream>>>(emb, eb);

  // zero hidden state rings + barrier + output accumulator
  hipMemsetAsync(h1f, 0, (size_t)3 * 2 * kB * kH * 4, stream);  // h1f,h2f,h3f contiguous
  hipMemsetAsync(h1b, 0, (size_t)3 * 2 * kB * kH * 2, stream);  // h1b,h2b,h3b contiguous
  hipMemsetAsync(bar, 0, 1024, stream);
  hipMemsetAsync(d_out, 0, (size_t)kB * 4, stream);

  Params P;
  P.target = target; P.bosp = bosp; P.b_out = b_out;
  P.w1i = w1i; P.w1h = w1h; P.w2i = w2i; P.w2h = w2h; P.w3i = w3i; P.w3h = w3h;
  P.wout = wo; P.embb = eb;
  P.bi1 = bi1; P.bh1 = bh1; P.bi2 = bi2; P.bh2 = bh2; P.bi3 = bi3; P.bh3 = bh3;
  P.gi1 = gi1; P.gi2 = gi2; P.gi3 = gi3;
  P.h1f = h1f; P.h2f = h2f; P.h3f = h3f;
  P.h1b = h1b; P.h2b = h2b; P.h3b = h3b;
  P.lp = (float*)d_out;
  P.acnt = bar; P.gflag = bar + 128;   // 8 lines each, 64B apart

  rnn_main<<<dim3(NB), dim3(256), 0, stream>>>(P);
}

// Round 4
// 13589.000 us; speedup vs baseline: 3.7762x; 1.0341x over previous
//
#include <hip/hip_runtime.h>
#include <hip/hip_bf16.h>
#include <cstdint>

// Problem constants
constexpr int kT = 128;    // sequence length
constexpr int kB = 256;    // batch
constexpr int kE = 512;    // embed dim
constexpr int kH = 1024;   // hidden
constexpr int kV = 348;    // vocab
constexpr int kNG = 3072;  // 3*H gate width
constexpr int NB = 224;    // grid size (<= 256 CUs -> all blocks resident)

typedef short s8v __attribute__((ext_vector_type(8)));   // 8 bf16 (4 VGPRs) MFMA operand
typedef float f4v __attribute__((ext_vector_type(4)));   // MFMA accumulator
typedef unsigned short u16;

__device__ __forceinline__ u16 f2bf(float x) {
  unsigned int u = __builtin_bit_cast(unsigned int, x);
  u += 0x7fffu + ((u >> 16) & 1u);          // RNE
  return (u16)(u >> 16);
}

// ---- device-coherent (cross-XCD) accessors: sc1 ops to the MALL coherent
// point. No cache-maintenance side effects (unlike fences). ----
__device__ __forceinline__ float ldv_f32(const float* p) {
  return __hip_atomic_load(p, __ATOMIC_RELAXED, __HIP_MEMORY_SCOPE_AGENT);
}
__device__ __forceinline__ void stv_f32(float* p, float v) {
  __hip_atomic_store(p, v, __ATOMIC_RELAXED, __HIP_MEMORY_SCOPE_AGENT);
}
__device__ __forceinline__ uint64_t ldv_u64(const void* p) {
  return __hip_atomic_load((const uint64_t*)p, __ATOMIC_RELAXED, __HIP_MEMORY_SCOPE_AGENT);
}
__device__ __forceinline__ void stv_u16(u16* p, u16 v) {
  __hip_atomic_store(p, v, __ATOMIC_RELAXED, __HIP_MEMORY_SCOPE_AGENT);
}

// gate-major n = gate*H + j  ->  interleaved col = 48*(j/16) + 16*gate + (j%16)
__device__ __forceinline__ int permn(int n) {
  int gate = n >> 10, j = n & 1023;
  return ((j >> 4) * 48) + gate * 16 + (j & 15);
}

struct Params {
  const int* target; const int* bosp; const float* b_out;
  const u16 *w1i, *w1h, *w2i, *w2h, *w3i, *w3h, *wout, *embb;
  const float *bi1, *bh1, *bi2, *bh2, *bi3, *bh3;
  float *gi1, *gi2, *gi3;       // [2][B][NG] fp32 (permuted col layout)  [sc1]
  float *h1f, *h2f, *h3f;       // [2][B][H] fp32 state                   [block-local, cached]
  u16   *h1b, *h2b, *h3b;       // [2][B][H] bf16 state                   [sc1]
  float *lp;                    // [B] output accumulator (= d_out)       [block-local, cached]
  unsigned *acnt; unsigned *gflag; // grid barrier state (zeroed each call)
};

union SMem {
  struct { u16 A[128 * 72]; u16 Bw[192 * 72]; } mm;  // +8 short pad per row
  float logits[16 * 400];
};

// ---- grid barrier v3: zero fences. sc1 write-through stores are globally
// visible once vmcnt drains (done per-wave before s_barrier); flags are
// relaxed agent atomics. 32 arrival lines (monotonic), block 0 gathers and
// publishes to 32 replicated go-flags. ----
__device__ __forceinline__ void gbar(unsigned* acnt, unsigned* gflag, unsigned s) {
  asm volatile("s_waitcnt vmcnt(0)" ::: "memory");   // each wave drains its sc1 stores
  __syncthreads();
  if (threadIdx.x == 0) {
    const unsigned g = blockIdx.x & 31u;
    __hip_atomic_fetch_add(&acnt[g * 16], 1u, __ATOMIC_RELAXED, __HIP_MEMORY_SCOPE_AGENT);
    if (blockIdx.x == 0) {
      for (;;) {
        unsigned sum = 0;
#pragma unroll
        for (int i = 0; i < 32; ++i)
          sum += __hip_atomic_load(&acnt[i * 16], __ATOMIC_RELAXED, __HIP_MEMORY_SCOPE_AGENT);
        if (sum >= (unsigned)NB * (s + 1u)) break;
        __builtin_amdgcn_s_sleep(4);
      }
#pragma unroll
      for (int i = 0; i < 32; ++i)
        __hip_atomic_store(&gflag[i * 16], s + 1u, __ATOMIC_RELAXED, __HIP_MEMORY_SCOPE_AGENT);
    } else {
      while (__hip_atomic_load(&gflag[g * 16], __ATOMIC_RELAXED, __HIP_MEMORY_SCOPE_AGENT) <= s)
        __builtin_amdgcn_s_sleep(8);
    }
    asm volatile("" ::: "memory");
  }
  __syncthreads();
}

// ---------------- S stage: gi = A @ W^T + bias (tile 128x128, BK=64) ----------------
// DEVC: A operand is cross-block state (h*b) -> sc1 loads. Weights cached.
template<int K, bool EMB, bool DEVC>
__device__ void do_S(SMem& sm, const u16* __restrict__ Asrc, const u16* __restrict__ Wp,
                     const float* __restrict__ biasP, float* __restrict__ giOut,
                     const int* __restrict__ target, int bos, int u, int tile)
{
  const int mt = tile / 24, nt = tile % 24;
  const int b0 = mt * 128, n0 = nt * 128;
  const int t = threadIdx.x, lane = t & 63, wv = t >> 6;
  const int wm = wv >> 1, wn = wv & 1;           // wave tile: 64 rows x 64 cols
  const int li = lane & 15, q = lane >> 4;
  f4v acc[4][4];
#pragma unroll
  for (int i = 0; i < 4; ++i)
#pragma unroll
    for (int j = 0; j < 4; ++j) acc[i][j] = f4v{0.f, 0.f, 0.f, 0.f};

  const int c8 = (t & 7) * 8, r0 = t >> 3;
  for (int k0 = 0; k0 < K; k0 += 64) {
    __syncthreads();
#pragma unroll
    for (int p = 0; p < 4; ++p) {                // A: 128 rows
      int r = r0 + 32 * p;
      if (EMB) {
        int b = b0 + r;
        int tok = (u == 0) ? bos : target[b * kT + (u - 1)];
        const u16* src = Asrc + (size_t)tok * kE;
        *(uint4*)&sm.mm.A[r * 72 + c8] = *(const uint4*)&src[k0 + c8];
      } else if (DEVC) {
        const u16* src = Asrc + (size_t)(b0 + r) * K + k0 + c8;
        uint64_t lo = ldv_u64(src), hi = ldv_u64(src + 4);
        *(uint64_t*)&sm.mm.A[r * 72 + c8] = lo;
        *(uint64_t*)&sm.mm.A[r * 72 + c8 + 4] = hi;
      } else {
        const u16* src = Asrc + (size_t)(b0 + r) * K;
        *(uint4*)&sm.mm.A[r * 72 + c8] = *(const uint4*)&src[k0 + c8];
      }
    }
#pragma unroll
    for (int p = 0; p < 4; ++p) {                // B: 128 rows (weights, cached)
      int r = r0 + 32 * p;
      *(uint4*)&sm.mm.Bw[r * 72 + c8] = *(const uint4*)&Wp[(size_t)(n0 + r) * K + k0 + c8];
    }
    __syncthreads();
#pragma unroll
    for (int kk = 0; kk < 64; kk += 32) {
      int lk = kk + q * 8;
      s8v a[4], bv[4];
#pragma unroll
      for (int m2 = 0; m2 < 4; ++m2)
        a[m2] = *(const s8v*)&sm.mm.A[(64 * wm + 16 * m2 + li) * 72 + lk];
#pragma unroll
      for (int f = 0; f < 4; ++f)
        bv[f] = *(const s8v*)&sm.mm.Bw[(64 * wn + 16 * f + li) * 72 + lk];
#pragma unroll
      for (int m2 = 0; m2 < 4; ++m2)
#pragma unroll
        for (int f = 0; f < 4; ++f)
          acc[m2][f] = __builtin_amdgcn_mfma_f32_16x16x32_bf16(a[m2], bv[f], acc[m2][f], 0, 0, 0);
    }
  }
#pragma unroll
  for (int m2 = 0; m2 < 4; ++m2)
#pragma unroll
    for (int f = 0; f < 4; ++f) {
      int n = n0 + 64 * wn + 16 * f + li;
      float bias = biasP[n];
#pragma unroll
      for (int r = 0; r < 4; ++r) {
        int b = b0 + 64 * wm + 16 * m2 + 4 * q + r;   // C/D: col=lane&15, row=(lane>>4)*4+reg
        stv_f32(&giOut[(size_t)b * kNG + n], acc[m2][f][r] + bias);
      }
    }
}

// ---------------- F stage: gh = h_prev @ Whh^T (tile 128x96) + fused GRU update ----------------
__device__ void do_F(SMem& sm, const u16* __restrict__ hbPrev, const float* __restrict__ hfPrev,
                     const u16* __restrict__ Whp, const float* __restrict__ bhP,
                     const float* __restrict__ giIn, float* __restrict__ hfOut,
                     u16* __restrict__ hbOut, int tile)
{
  const int mt = tile >> 5, jt = tile & 31;
  const int b0 = mt * 128, j0 = jt * 32, n0 = jt * 96;
  const int t = threadIdx.x, lane = t & 63, wv = t >> 6;
  const int wm = wv >> 1, wg = wv & 1;           // wave tile: 64 rows x 48 perm-cols
  const int li = lane & 15, q = lane >> 4;
  f4v acc[4][3];
#pragma unroll
  for (int i = 0; i < 4; ++i)
#pragma unroll
    for (int g = 0; g < 3; ++g) acc[i][g] = f4v{0.f, 0.f, 0.f, 0.f};

  const int c8 = (t & 7) * 8, r0 = t >> 3;
  for (int k0 = 0; k0 < kH; k0 += 64) {
    __syncthreads();
#pragma unroll
    for (int p = 0; p < 4; ++p) {                // A: 128 rows of h (cross-block -> sc1)
      int r = r0 + 32 * p;
      const u16* src = hbPrev + (size_t)(b0 + r) * kH + k0 + c8;
      uint64_t lo = ldv_u64(src), hi = ldv_u64(src + 4);
      *(uint64_t*)&sm.mm.A[r * 72 + c8] = lo;
      *(uint64_t*)&sm.mm.A[r * 72 + c8 + 4] = hi;
    }
#pragma unroll
    for (int p = 0; p < 3; ++p) {                // B: 96 rows (weights, cached)
      int r = r0 + 32 * p;
      *(uint4*)&sm.mm.Bw[r * 72 + c8] = *(const uint4*)&Whp[(size_t)(n0 + r) * kH + k0 + c8];
    }
    __syncthreads();
#pragma unroll
    for (int kk = 0; kk < 64; kk += 32) {
      int lk = kk + q * 8;
      s8v a[4], bv[3];
#pragma unroll
      for (int m2 = 0; m2 < 4; ++m2)
        a[m2] = *(const s8v*)&sm.mm.A[(64 * wm + 16 * m2 + li) * 72 + lk];
#pragma unroll
      for (int g = 0; g < 3; ++g)
        bv[g] = *(const s8v*)&sm.mm.Bw[(48 * wg + 16 * g + li) * 72 + lk];
#pragma unroll
      for (int m2 = 0; m2 < 4; ++m2)
#pragma unroll
        for (int g = 0; g < 3; ++g)
          acc[m2][g] = __builtin_amdgcn_mfma_f32_16x16x32_bf16(a[m2], bv[g], acc[m2][g], 0, 0, 0);
    }
  }
  // fused GRU update: lane-aligned r,z,n triples thanks to permuted weight layout
  {
    int j = j0 + 16 * wg + li;
    int cr = n0 + 48 * wg + li;
    float bhr = bhP[cr], bhz = bhP[cr + 16], bhn = bhP[cr + 32];
    // phase 1: batch-issue all cross-block gi loads (sc1) + local h loads
    float gr[4][4], gz[4][4], gn[4][4], hold[4][4];
#pragma unroll
    for (int m2 = 0; m2 < 4; ++m2)
#pragma unroll
      for (int r = 0; r < 4; ++r) {
        int b = b0 + 64 * wm + 16 * m2 + 4 * q + r;
        const float* gib = giIn + (size_t)b * kNG;
        gr[m2][r] = ldv_f32(gib + cr);
        gz[m2][r] = ldv_f32(gib + cr + 16);
        gn[m2][r] = ldv_f32(gib + cr + 32);
        hold[m2][r] = hfPrev[(size_t)b * kH + j];
      }
    // phase 2: compute + store
#pragma unroll
    for (int m2 = 0; m2 < 4; ++m2) {
#pragma unroll
      for (int r = 0; r < 4; ++r) {
        int b = b0 + 64 * wm + 16 * m2 + 4 * q + r;
        float ghr = acc[m2][0][r] + bhr;
        float ghz = acc[m2][1][r] + bhz;
        float ghn = acc[m2][2][r] + bhn;
        float rr = gr[m2][r] + ghr;
        float zz = gz[m2][r] + ghz;
        float rg = 1.f / (1.f + __expf(-rr));
        float zg = 1.f / (1.f + __expf(-zz));
        float np = gn[m2][r] + rg * ghn;
        float nh = 2.f / (1.f + __expf(-2.f * np)) - 1.f;   // tanh
        float hnew = (1.f - zg) * nh + zg * hold[m2][r];
        hfOut[(size_t)b * kH + j] = hnew;                   // block-local, cached
        stv_u16(&hbOut[(size_t)b * kH + j], f2bf(hnew));    // cross-block, sc1
      }
    }
  }
}

// ---------------- E stage: logits + log_softmax + target gather (16 rows/tile) ----------------
__device__ void do_E(SMem& sm, const u16* __restrict__ h3b, const u16* __restrict__ wo,
                     const float* __restrict__ b_out, const int* __restrict__ target,
                     float* __restrict__ lp, int u, int tile)
{
  const int b0 = tile * 16;
  const int t = threadIdx.x, lane = t & 63, wv = t >> 6;
  const int li = lane & 15, q = lane >> 4;
  f4v acc[6];
#pragma unroll
  for (int f = 0; f < 6; ++f) acc[f] = f4v{0.f, 0.f, 0.f, 0.f};

  for (int k0 = 0; k0 < kH; k0 += 32) {
    int lk = k0 + q * 8;
    union { uint64_t q2[2]; s8v v; } ua;
    const u16* ap = h3b + (size_t)(b0 + li) * kH + lk;
    ua.q2[0] = ldv_u64(ap); ua.q2[1] = ldv_u64(ap + 4);     // cross-block h3 -> sc1
#pragma unroll
    for (int f = 0; f < 6; ++f) {
      s8v bb = *(const s8v*)&wo[(size_t)(96 * wv + 16 * f + li) * kH + lk]; // cached
      acc[f] = __builtin_amdgcn_mfma_f32_16x16x32_bf16(ua.v, bb, acc[f], 0, 0, 0);
    }
  }
  __syncthreads();   // protect sm.logits against previous tile's softmax reads
#pragma unroll
  for (int f = 0; f < 6; ++f) {
    int n = 96 * wv + 16 * f + li;
    if (n < kV) {
      float bo = b_out[n];
#pragma unroll
      for (int r = 0; r < 4; ++r) {
        int m = 4 * q + r;
        sm.logits[m * 400 + n] = acc[f][r] + bo;
      }
    }
  }
  __syncthreads();
  int m = 4 * wv + q;
  int b = b0 + m;
  float mx = -1e30f;
  for (int cc = li; cc < kV; cc += 16) mx = fmaxf(mx, sm.logits[m * 400 + cc]);
#pragma unroll
  for (int d = 1; d < 16; d <<= 1) mx = fmaxf(mx, __shfl_xor(mx, d, 16));
  float se = 0.f;
  for (int cc = li; cc < kV; cc += 16) se += __expf(sm.logits[m * 400 + cc] - mx);
#pragma unroll
  for (int d = 1; d < 16; d <<= 1) se += __shfl_xor(se, d, 16);
  int tgt = target[b * kT + u];
  float logp = sm.logits[m * 400 + tgt] - mx - __logf(se);
  if (li == 0) lp[b] += logp;   // block-local accumulator, cached
}

// ---------------- main persistent kernel ----------------
__global__ __launch_bounds__(256, 1) void rnn_main(Params P)
{
  __shared__ SMem sm;
  const int bid = blockIdx.x;
  const int bos = P.bosp[0];
  const size_t GI = (size_t)kB * kNG, HS = (size_t)kB * kH;

  for (int s = 0; s < kT + 6; ++s) {
    if (bid < 24) {                        // S1: gi1[u]  u=s   (24 blocks x 2 tiles)
      int u = s;
      if (u < kT)
        for (int tt = 0; tt < 2; ++tt)
          do_S<kE, true, false>(sm, P.embb, P.w1i, P.bi1, P.gi1 + (size_t)(u & 1) * GI,
                                P.target, bos, u, bid * 2 + tt);
    } else if (bid < 56) {                 // F1: h1[u]  u=s-1  (32 blocks x 2 tiles)
      int u = s - 1;
      if (u >= 0 && u < kT)
        for (int tt = 0; tt < 2; ++tt)
          do_F(sm, P.h1b + (size_t)((u - 1) & 1) * HS, P.h1f + (size_t)((u - 1) & 1) * HS,
               P.w1h, P.bh1, P.gi1 + (size_t)(u & 1) * GI,
               P.h1f + (size_t)(u & 1) * HS, P.h1b + (size_t)(u & 1) * HS, (bid - 24) * 2 + tt);
    } else if (bid < 104) {                // S2: gi2[u]  u=s-2 (48 blocks x 1 tile)
      int u = s - 2;
      if (u >= 0 && u < kT)
        do_S<kH, false, true>(sm, P.h1b + (size_t)(u & 1) * HS, P.w2i, P.bi2,
                              P.gi2 + (size_t)(u & 1) * GI, P.target, bos, u, bid - 56);
    } else if (bid < 136) {                // F2: h2[u]  u=s-3
      int u = s - 3;
      if (u >= 0 && u < kT)
        for (int tt = 0; tt < 2; ++tt)
          do_F(sm, P.h2b + (size_t)((u - 1) & 1) * HS, P.h2f + (size_t)((u - 1) & 1) * HS,
               P.w2h, P.bh2, P.gi2 + (size_t)(u & 1) * GI,
               P.h2f + (size_t)(u & 1) * HS, P.h2b + (size_t)(u & 1) * HS, (bid - 104) * 2 + tt);
    } else if (bid < 184) {                // S3: gi3[u]  u=s-4
      int u = s - 4;
      if (u >= 0 && u < kT)
        do_S<kH, false, true>(sm, P.h2b + (size_t)(u & 1) * HS, P.w3i, P.bi3,
                              P.gi3 + (size_t)(u & 1) * GI, P.target, bos, u, bid - 136);
    } else if (bid < 216) {                // F3: h3[u]  u=s-5
      int u = s - 5;
      if (u >= 0 && u < kT)
        for (int tt = 0; tt < 2; ++tt)
          do_F(sm, P.h3b + (size_t)((u - 1) & 1) * HS, P.h3f + (size_t)((u - 1) & 1) * HS,
               P.w3h, P.bh3, P.gi3 + (size_t)(u & 1) * GI,
               P.h3f + (size_t)(u & 1) * HS, P.h3b + (size_t)(u & 1) * HS, (bid - 184) * 2 + tt);
    } else {                               // E: logits/logsoftmax  u=s-6 (8 blocks x 2 tiles)
      int u = s - 6;
      if (u >= 0 && u < kT)
        for (int tt = 0; tt < 2; ++tt)
          do_E(sm, P.h3b + (size_t)(u & 1) * HS, P.wout, P.b_out, P.target, P.lp, u,
               (bid - 216) * 2 + tt);
    }
    gbar(P.acnt, P.gflag, (unsigned)s);
  }
}

// ---------------- conversion / init kernels ----------------
__global__ void k_conv_w(const float* __restrict__ w, u16* __restrict__ wp, int K, int logK) {
  int idx = blockIdx.x * 256 + threadIdx.x;
  if (idx >= kNG * K) return;
  int n = idx >> logK, k = idx & (K - 1);
  wp[(size_t)permn(n) * K + k] = f2bf(w[idx]);
}
__global__ void k_conv_b(const float* __restrict__ b, float* __restrict__ bp) {
  int idx = blockIdx.x * 256 + threadIdx.x;
  if (idx < kNG) bp[permn(idx)] = b[idx];
}
__global__ void k_conv_wout(const float* __restrict__ w, u16* __restrict__ wp) {
  int idx = blockIdx.x * 256 + threadIdx.x;
  if (idx >= 384 * kH) return;
  int n = idx >> 10, k = idx & 1023;
  wp[idx] = (n < kV) ? f2bf(w[(size_t)n * kH + k]) : (u16)0;
}
__global__ void k_conv_emb(const float* __restrict__ e, u16* __restrict__ ep) {
  int idx = blockIdx.x * 256 + threadIdx.x;
  if (idx < kV * kE) ep[idx] = f2bf(e[idx]);
}

extern "C" void kernel_launch(void* const* d_in, const int* in_sizes, int n_in,
                              void* d_out, int out_size, void* d_ws, size_t ws_size,
                              hipStream_t stream)
{
  const int*   target = (const int*)d_in[0];
  const int*   bosp   = (const int*)d_in[1];
  const float* emb    = (const float*)d_in[2];
  const float* w_ih1  = (const float*)d_in[3];
  const float* w_hh1  = (const float*)d_in[4];
  const float* b_ih1  = (const float*)d_in[5];
  const float* b_hh1  = (const float*)d_in[6];
  const float* w_ih2  = (const float*)d_in[7];
  const float* w_hh2  = (const float*)d_in[8];
  const float* b_ih2  = (const float*)d_in[9];
  const float* b_hh2  = (const float*)d_in[10];
  const float* w_ih3  = (const float*)d_in[11];
  const float* w_hh3  = (const float*)d_in[12];
  const float* b_ih3  = (const float*)d_in[13];
  const float* b_hh3  = (const float*)d_in[14];
  const float* w_out  = (const float*)d_in[15];
  const float* b_out  = (const float*)d_in[16];

  char* ws = (char*)d_ws;
  size_t off = 0;
  auto alloc = [&](size_t bytes) -> void* {
    void* p = ws + off;
    off = (off + bytes + 511) & ~(size_t)511;
    return p;
  };
  u16* w1i = (u16*)alloc((size_t)kNG * kE * 2);
  u16* w1h = (u16*)alloc((size_t)kNG * kH * 2);
  u16* w2i = (u16*)alloc((size_t)kNG * kH * 2);
  u16* w2h = (u16*)alloc((size_t)kNG * kH * 2);
  u16* w3i = (u16*)alloc((size_t)kNG * kH * 2);
  u16* w3h = (u16*)alloc((size_t)kNG * kH * 2);
  u16* wo  = (u16*)alloc((size_t)384 * kH * 2);
  u16* eb  = (u16*)alloc((size_t)kV * kE * 2);
  float* bi1 = (float*)alloc(kNG * 4);
  float* bh1 = (float*)alloc(kNG * 4);
  float* bi2 = (float*)alloc(kNG * 4);
  float* bh2 = (float*)alloc(kNG * 4);
  float* bi3 = (float*)alloc(kNG * 4);
  float* bh3 = (float*)alloc(kNG * 4);
  float* gi1 = (float*)alloc((size_t)2 * kB * kNG * 4);
  float* gi2 = (float*)alloc((size_t)2 * kB * kNG * 4);
  float* gi3 = (float*)alloc((size_t)2 * kB * kNG * 4);
  float* h1f = (float*)alloc((size_t)2 * kB * kH * 4);
  float* h2f = (float*)alloc((size_t)2 * kB * kH * 4);
  float* h3f = (float*)alloc((size_t)2 * kB * kH * 4);
  u16* h1b = (u16*)alloc((size_t)2 * kB * kH * 2);
  u16* h2b = (u16*)alloc((size_t)2 * kB * kH * 2);
  u16* h3b = (u16*)alloc((size_t)2 * kB * kH * 2);
  unsigned* bar = (unsigned*)alloc(4096);
  (void)ws_size; (void)in_sizes; (void)n_in; (void)out_size;

  // weight/bias/embedding conversion (runs every call)
  k_conv_w<<<(kNG * kE + 255) / 256, 256, 0, stream>>>(w_ih1, w1i, kE, 9);
  k_conv_w<<<(kNG * kH + 255) / 256, 256, 0, stream>>>(w_hh1, w1h, kH, 10);
  k_conv_w<<<(kNG * kH + 255) / 256, 256, 0, stream>>>(w_ih2, w2i, kH, 10);
  k_conv_w<<<(kNG * kH + 255) / 256, 256, 0, stream>>>(w_hh2, w2h, kH, 10);
  k_conv_w<<<(kNG * kH + 255) / 256, 256, 0, stream>>>(w_ih3, w3i, kH, 10);
  k_conv_w<<<(kNG * kH + 255) / 256, 256, 0, stream>>>(w_hh3, w3h, kH, 10);
  k_conv_b<<<(kNG + 255) / 256, 256, 0, stream>>>(b_ih1, bi1);
  k_conv_b<<<(kNG + 255) / 256, 256, 0, stream>>>(b_hh1, bh1);
  k_conv_b<<<(kNG + 255) / 256, 256, 0, stream>>>(b_ih2, bi2);
  k_conv_b<<<(kNG + 255) / 256, 256, 0, stream>>>(b_hh2, bh2);
  k_conv_b<<<(kNG + 255) / 256, 256, 0, stream>>>(b_ih3, bi3);
  k_conv_b<<<(kNG + 255) / 256, 256, 0, stream>>>(b_hh3, bh3);
  k_conv_wout<<<(384 * kH + 255) / 256, 256, 0, stream>>>(w_out, wo);
  k_conv_emb<<<(kV * kE + 255) / 256, 256, 0, stream>>>(emb, eb);

  // zero hidden state rings + barrier + output accumulator
  hipMemsetAsync(h1f, 0, (size_t)3 * 2 * kB * kH * 4, stream);  // h1f,h2f,h3f contiguous
  hipMemsetAsync(h1b, 0, (size_t)3 * 2 * kB * kH * 2, stream);  // h1b,h2b,h3b contiguous
  hipMemsetAsync(bar, 0, 4096, stream);
  hipMemsetAsync(d_out, 0, (size_t)kB * 4, stream);

  Params P;
  P.target = target; P.bosp = bosp; P.b_out = b_out;
  P.w1i = w1i; P.w1h = w1h; P.w2i = w2i; P.w2h = w2h; P.w3i = w3i; P.w3h = w3h;
  P.wout = wo; P.embb = eb;
  P.bi1 = bi1; P.bh1 = bh1; P.bi2 = bi2; P.bh2 = bh2; P.bi3 = bi3; P.bh3 = bh3;
  P.gi1 = gi1; P.gi2 = gi2; P.gi3 = gi3;
  P.h1f = h1f; P.h2f = h2f; P.h3f = h3f;
  P.h1b = h1b; P.h2b = h2b; P.h3b = h3b;
  P.lp = (float*)d_out;
  P.acnt = bar; P.gflag = bar + 512;   // 32 lines each, 64B apart

  rnn_main<<<dim3(NB), dim3(256), 0, stream>>>(P);
}

// Round 5
// 8596.402 us; speedup vs baseline: 5.9693x; 1.5808x over previous
//
#include <hip/hip_runtime.h>
#include <hip/hip_bf16.h>
#include <cstdint>

// Problem constants
constexpr int kT = 128;    // sequence length
constexpr int kB = 256;    // batch
constexpr int kE = 512;    // embed dim
constexpr int kH = 1024;   // hidden
constexpr int kV = 348;    // vocab
constexpr int kNG = 3072;  // 3*H gate width
constexpr int NB = 208;    // 192 layer blocks + 16 E blocks (<=256 CUs, all resident)

typedef short s8v __attribute__((ext_vector_type(8)));   // 8 bf16 MFMA operand
typedef float f4v __attribute__((ext_vector_type(4)));   // MFMA accumulator
typedef unsigned short u16;

__device__ __forceinline__ u16 f2bf(float x) {
  unsigned int u = __builtin_bit_cast(unsigned int, x);
  u += 0x7fffu + ((u >> 16) & 1u);          // RNE
  return (u16)(u >> 16);
}

// device-coherent (cross-XCD) accessors: bypass L1/L2, hit MALL coherent point
__device__ __forceinline__ uint64_t ldv_u64(const void* p) {
  return __hip_atomic_load((const uint64_t*)p, __ATOMIC_RELAXED, __HIP_MEMORY_SCOPE_AGENT);
}
__device__ __forceinline__ void stv_u16(u16* p, u16 v) {
  __hip_atomic_store(p, v, __ATOMIC_RELAXED, __HIP_MEMORY_SCOPE_AGENT);
}

// gate-major n = gate*H + j  ->  interleaved col = 48*(j/16) + 16*gate + (j%16)
__device__ __forceinline__ int permn(int n) {
  int gate = n >> 10, j = n & 1023;
  return ((j >> 4) * 48) + gate * 16 + (j & 15);
}

struct Params {
  const int* target; const int* bosp; const float* b_out;
  const u16 *w1i, *w1h, *w2i, *w2h, *w3i, *w3h, *wout, *embb;
  const float *bi1, *bh1, *bi2, *bh2, *bi3, *bh3;
  float *h1f, *h2f, *h3f;       // [2][B][H] fp32 state (block-local, cached)
  u16   *h1b, *h2b, *h3b;       // [2][B][H] bf16 state (cross-block, sc1)
  float *lp;                    // [B] output accumulator (= d_out)
  unsigned *acnt; unsigned *gflag;
};

union SMem {
  struct { u16 A[128 * 72]; u16 B[96 * 72]; } mm;  // 32.3 KB, +8 short row pad
  float logits[16 * 400];
};

// ---- grid barrier: relaxed flag ops only, no fences (all cross-block data
// moves via sc1 write-through; vmcnt drain before arrival). ----
__device__ __forceinline__ void gbar(unsigned* acnt, unsigned* gflag, unsigned s) {
  asm volatile("s_waitcnt vmcnt(0)" ::: "memory");
  __syncthreads();
  if (threadIdx.x == 0) {
    const unsigned g = blockIdx.x & 31u;
    __hip_atomic_fetch_add(&acnt[g * 16], 1u, __ATOMIC_RELAXED, __HIP_MEMORY_SCOPE_AGENT);
    if (blockIdx.x == 0) {
      for (;;) {
        unsigned sum = 0;
#pragma unroll
        for (int i = 0; i < 32; ++i)
          sum += __hip_atomic_load(&acnt[i * 16], __ATOMIC_RELAXED, __HIP_MEMORY_SCOPE_AGENT);
        if (sum >= (unsigned)NB * (s + 1u)) break;
        __builtin_amdgcn_s_sleep(4);
      }
#pragma unroll
      for (int i = 0; i < 32; ++i)
        __hip_atomic_store(&gflag[i * 16], s + 1u, __ATOMIC_RELAXED, __HIP_MEMORY_SCOPE_AGENT);
    } else {
      while (__hip_atomic_load(&gflag[g * 16], __ATOMIC_RELAXED, __HIP_MEMORY_SCOPE_AGENT) <= s)
        __builtin_amdgcn_s_sleep(8);
    }
    asm volatile("" ::: "memory");
  }
  __syncthreads();
}

// ---------------- one matmul phase: acc{R,Z,N} += A(128xK) @ W(96xK)^T ----------------
// 1-deep register prefetch: loads for iter k+1 issued before MFMAs of iter k.
// EMB: A rows gathered from embedding table (cached); else sc1 loads of h-state.
template<int K, bool EMB>
__device__ __forceinline__ void mm_phase(SMem& sm, const u16* __restrict__ Asrc,
    const u16* __restrict__ W, int b0, int n0,
    f4v* aR, f4v* aZ, f4v* aN,
    const int* __restrict__ target, int bos, int u)
{
  const int t = threadIdx.x, lane = t & 63, wv = t >> 6;
  const int wm = wv >> 1, wg = wv & 1, li = lane & 15, q = lane >> 4;
  const int c8 = (t & 7) * 8, r0 = t >> 3;
  uint64_t raLo[4], raHi[4];
  uint4 rb[3];

  auto stage = [&](int k0) {
#pragma unroll
    for (int p = 0; p < 4; ++p) {                 // A: 128 rows
      int r = r0 + 32 * p;
      if (EMB) {
        int b = b0 + r;
        int tok = (u == 0) ? bos : target[b * kT + (u - 1)];
        uint4 v = *(const uint4*)&Asrc[(size_t)tok * K + k0 + c8];
        raLo[p] = ((uint64_t)v.y << 32) | v.x;
        raHi[p] = ((uint64_t)v.w << 32) | v.z;
      } else {
        const u16* src = Asrc + (size_t)(b0 + r) * K + k0 + c8;
        raLo[p] = ldv_u64(src); raHi[p] = ldv_u64(src + 4);
      }
    }
#pragma unroll
    for (int p = 0; p < 3; ++p) {                 // B: 96 weight rows (cached)
      int r = r0 + 32 * p;
      rb[p] = *(const uint4*)&W[(size_t)(n0 + r) * K + k0 + c8];
    }
  };

  stage(0);
  for (int it = 0; it < K / 64; ++it) {
    __syncthreads();                              // prev-iter LDS consumers done
#pragma unroll
    for (int p = 0; p < 4; ++p) {
      int r = r0 + 32 * p;
      *(uint64_t*)&sm.mm.A[r * 72 + c8] = raLo[p];
      *(uint64_t*)&sm.mm.A[r * 72 + c8 + 4] = raHi[p];
    }
#pragma unroll
    for (int p = 0; p < 3; ++p) {
      int r = r0 + 32 * p;
      *(uint4*)&sm.mm.B[r * 72 + c8] = rb[p];
    }
    __syncthreads();
    if (it + 1 < K / 64) stage((it + 1) * 64);    // prefetch overlaps MFMAs below
#pragma unroll
    for (int kk = 0; kk < 64; kk += 32) {
      int lk = kk + q * 8;
      s8v a[4], bv[3];
#pragma unroll
      for (int m2 = 0; m2 < 4; ++m2)
        a[m2] = *(const s8v*)&sm.mm.A[(64 * wm + 16 * m2 + li) * 72 + lk];
#pragma unroll
      for (int g = 0; g < 3; ++g)
        bv[g] = *(const s8v*)&sm.mm.B[(48 * wg + 16 * g + li) * 72 + lk];
#pragma unroll
      for (int m2 = 0; m2 < 4; ++m2) {
        aR[m2] = __builtin_amdgcn_mfma_f32_16x16x32_bf16(a[m2], bv[0], aR[m2], 0, 0, 0);
        aZ[m2] = __builtin_amdgcn_mfma_f32_16x16x32_bf16(a[m2], bv[1], aZ[m2], 0, 0, 0);
        aN[m2] = __builtin_amdgcn_mfma_f32_16x16x32_bf16(a[m2], bv[2], aN[m2], 0, 0, 0);
      }
    }
  }
}

// ---------------- merged layer stage: gi + gh + GRU update, tile 128b x 32j ----------------
template<int K1, bool L1>
__device__ void do_L(SMem& sm, const u16* __restrict__ xsrc,
                     const u16* __restrict__ hbPrev, const float* __restrict__ hfPrev,
                     const u16* __restrict__ Wih, const u16* __restrict__ Whh,
                     const float* __restrict__ biP, const float* __restrict__ bhP,
                     float* __restrict__ hfOut, u16* __restrict__ hbOut,
                     const int* __restrict__ target, int bos, int u, int mt, int jt)
{
  const int b0 = mt * 128, j0 = jt * 32, n0 = jt * 96;
  f4v aR[4], aZ[4], aNi[4], aNh[4];
#pragma unroll
  for (int i = 0; i < 4; ++i) {
    aR[i] = f4v{0.f,0.f,0.f,0.f}; aZ[i] = f4v{0.f,0.f,0.f,0.f};
    aNi[i] = f4v{0.f,0.f,0.f,0.f}; aNh[i] = f4v{0.f,0.f,0.f,0.f};
  }
  mm_phase<K1, L1>(sm, xsrc, Wih, b0, n0, aR, aZ, aNi, target, bos, u);   // gi
  mm_phase<kH, false>(sm, hbPrev, Whh, b0, n0, aR, aZ, aNh, target, bos, u); // gh

  const int t = threadIdx.x, lane = t & 63, wv = t >> 6;
  const int wm = wv >> 1, wg = wv & 1, li = lane & 15, q = lane >> 4;
  const int j = j0 + 16 * wg + li;
  const int cr = n0 + 48 * wg + li;
  const float bR = biP[cr] + bhP[cr];          // r,z biases sum
  const float bZ = biP[cr + 16] + bhP[cr + 16];
  const float biN = biP[cr + 32], bhN = bhP[cr + 32];
  float hold[4][4];
#pragma unroll
  for (int m2 = 0; m2 < 4; ++m2)
#pragma unroll
    for (int r = 0; r < 4; ++r) {
      int b = b0 + 64 * wm + 16 * m2 + 4 * q + r;
      hold[m2][r] = hfPrev[(size_t)b * kH + j];  // block-local, cached
    }
#pragma unroll
  for (int m2 = 0; m2 < 4; ++m2)
#pragma unroll
    for (int r = 0; r < 4; ++r) {
      int b = b0 + 64 * wm + 16 * m2 + 4 * q + r;
      float rg = 1.f / (1.f + __expf(-(aR[m2][r] + bR)));
      float zg = 1.f / (1.f + __expf(-(aZ[m2][r] + bZ)));
      float np = (aNi[m2][r] + biN) + rg * (aNh[m2][r] + bhN);
      float nh = 2.f / (1.f + __expf(-2.f * np)) - 1.f;   // tanh
      float hnew = (1.f - zg) * nh + zg * hold[m2][r];
      hfOut[(size_t)b * kH + j] = hnew;                   // local, cached
      stv_u16(&hbOut[(size_t)b * kH + j], f2bf(hnew));    // cross-block, sc1
    }
}

// ---------------- E stage: logits + log_softmax + gather (16 rows/block) ----------------
__device__ void do_E(SMem& sm, const u16* __restrict__ h3b, const u16* __restrict__ wo,
                     const float* __restrict__ b_out, const int* __restrict__ target,
                     float* __restrict__ lp, int u, int tile)
{
  const int b0 = tile * 16;
  const int t = threadIdx.x, lane = t & 63, wv = t >> 6;
  const int li = lane & 15, q = lane >> 4;
  f4v acc[6];
#pragma unroll
  for (int f = 0; f < 6; ++f) acc[f] = f4v{0.f, 0.f, 0.f, 0.f};

  const u16* ap = h3b + (size_t)(b0 + li) * kH + q * 8;
  uint64_t a0 = ldv_u64(ap), a1 = ldv_u64(ap + 4);     // prefetch k0=0
  for (int k0 = 0; k0 < kH; k0 += 32) {
    uint64_t p0 = 0, p1 = 0;
    if (k0 + 32 < kH) { p0 = ldv_u64(ap + k0 + 32); p1 = ldv_u64(ap + k0 + 36); }
    union { uint64_t w[2]; s8v v; } ua; ua.w[0] = a0; ua.w[1] = a1;
    int lk = k0 + q * 8;
#pragma unroll
    for (int f = 0; f < 6; ++f) {
      s8v bb = *(const s8v*)&wo[(size_t)(96 * wv + 16 * f + li) * kH + lk]; // cached
      acc[f] = __builtin_amdgcn_mfma_f32_16x16x32_bf16(ua.v, bb, acc[f], 0, 0, 0);
    }
    a0 = p0; a1 = p1;
  }
  __syncthreads();   // protect sm.logits from previous slot's softmax readers
#pragma unroll
  for (int f = 0; f < 6; ++f) {
    int n = 96 * wv + 16 * f + li;
    if (n < kV) {
      float bo = b_out[n];
#pragma unroll
      for (int r = 0; r < 4; ++r)
        sm.logits[(4 * q + r) * 400 + n] = acc[f][r] + bo;
    }
  }
  __syncthreads();
  int m = 4 * wv + q;
  int b = b0 + m;
  float mx = -1e30f;
  for (int cc = li; cc < kV; cc += 16) mx = fmaxf(mx, sm.logits[m * 400 + cc]);
#pragma unroll
  for (int d = 1; d < 16; d <<= 1) mx = fmaxf(mx, __shfl_xor(mx, d, 16));
  float se = 0.f;
  for (int cc = li; cc < kV; cc += 16) se += __expf(sm.logits[m * 400 + cc] - mx);
#pragma unroll
  for (int d = 1; d < 16; d <<= 1) se += __shfl_xor(se, d, 16);
  int tgt = target[b * kT + u];
  float logp = sm.logits[m * 400 + tgt] - mx - __logf(se);
  if (li == 0) lp[b] += logp;
}

// ---------------- main persistent kernel ----------------
__global__ __launch_bounds__(256, 1) void rnn_main(Params P)
{
  __shared__ SMem sm;
  const int bid = blockIdx.x;
  const int bos = P.bosp[0];
  const size_t HS = (size_t)kB * kH;

  // layer blocks: local in [0,64): mt-pair sharing weights sits 8 bids apart (same XCD, bid%8)
  const int local = bid & 63;
  const int mt = (local >> 3) & 1;
  const int jt = (local & 7) | ((local >> 4) << 3);

  for (int s = 0; s < kT + 3; ++s) {
    if (bid < 64) {                        // layer 1, u = s
      int u = s;
      if (u < kT)
        do_L<kE, true>(sm, P.embb,
                       P.h1b + (size_t)((u - 1) & 1) * HS, P.h1f + (size_t)((u - 1) & 1) * HS,
                       P.w1i, P.w1h, P.bi1, P.bh1,
                       P.h1f + (size_t)(u & 1) * HS, P.h1b + (size_t)(u & 1) * HS,
                       P.target, bos, u, mt, jt);
    } else if (bid < 128) {                // layer 2, u = s-1
      int u = s - 1;
      if (u >= 0 && u < kT)
        do_L<kH, false>(sm, P.h1b + (size_t)(u & 1) * HS,
                        P.h2b + (size_t)((u - 1) & 1) * HS, P.h2f + (size_t)((u - 1) & 1) * HS,
                        P.w2i, P.w2h, P.bi2, P.bh2,
                        P.h2f + (size_t)(u & 1) * HS, P.h2b + (size_t)(u & 1) * HS,
                        P.target, bos, u, mt, jt);
    } else if (bid < 192) {                // layer 3, u = s-2
      int u = s - 2;
      if (u >= 0 && u < kT)
        do_L<kH, false>(sm, P.h2b + (size_t)(u & 1) * HS,
                        P.h3b + (size_t)((u - 1) & 1) * HS, P.h3f + (size_t)((u - 1) & 1) * HS,
                        P.w3i, P.w3h, P.bi3, P.bh3,
                        P.h3f + (size_t)(u & 1) * HS, P.h3b + (size_t)(u & 1) * HS,
                        P.target, bos, u, mt, jt);
    } else {                               // E, u = s-3
      int u = s - 3;
      if (u >= 0 && u < kT)
        do_E(sm, P.h3b + (size_t)(u & 1) * HS, P.wout, P.b_out, P.target, P.lp, u, bid - 192);
    }
    gbar(P.acnt, P.gflag, (unsigned)s);
  }
}

// ---------------- conversion / init kernels ----------------
__global__ void k_conv_w(const float* __restrict__ w, u16* __restrict__ wp, int K, int logK) {
  int idx = blockIdx.x * 256 + threadIdx.x;
  if (idx >= kNG * K) return;
  int n = idx >> logK, k = idx & (K - 1);
  wp[(size_t)permn(n) * K + k] = f2bf(w[idx]);
}
__global__ void k_conv_b(const float* __restrict__ b, float* __restrict__ bp) {
  int idx = blockIdx.x * 256 + threadIdx.x;
  if (idx < kNG) bp[permn(idx)] = b[idx];
}
__global__ void k_conv_wout(const float* __restrict__ w, u16* __restrict__ wp) {
  int idx = blockIdx.x * 256 + threadIdx.x;
  if (idx >= 384 * kH) return;
  int n = idx >> 10, k = idx & 1023;
  wp[idx] = (n < kV) ? f2bf(w[(size_t)n * kH + k]) : (u16)0;
}
__global__ void k_conv_emb(const float* __restrict__ e, u16* __restrict__ ep) {
  int idx = blockIdx.x * 256 + threadIdx.x;
  if (idx < kV * kE) ep[idx] = f2bf(e[idx]);
}

extern "C" void kernel_launch(void* const* d_in, const int* in_sizes, int n_in,
                              void* d_out, int out_size, void* d_ws, size_t ws_size,
                              hipStream_t stream)
{
  const int*   target = (const int*)d_in[0];
  const int*   bosp   = (const int*)d_in[1];
  const float* emb    = (const float*)d_in[2];
  const float* w_ih1  = (const float*)d_in[3];
  const float* w_hh1  = (const float*)d_in[4];
  const float* b_ih1  = (const float*)d_in[5];
  const float* b_hh1  = (const float*)d_in[6];
  const float* w_ih2  = (const float*)d_in[7];
  const float* w_hh2  = (const float*)d_in[8];
  const float* b_ih2  = (const float*)d_in[9];
  const float* b_hh2  = (const float*)d_in[10];
  const float* w_ih3  = (const float*)d_in[11];
  const float* w_hh3  = (const float*)d_in[12];
  const float* b_ih3  = (const float*)d_in[13];
  const float* b_hh3  = (const float*)d_in[14];
  const float* w_out  = (const float*)d_in[15];
  const float* b_out  = (const float*)d_in[16];

  char* ws = (char*)d_ws;
  size_t off = 0;
  auto alloc = [&](size_t bytes) -> void* {
    void* p = ws + off;
    off = (off + bytes + 511) & ~(size_t)511;
    return p;
  };
  u16* w1i = (u16*)alloc((size_t)kNG * kE * 2);
  u16* w1h = (u16*)alloc((size_t)kNG * kH * 2);
  u16* w2i = (u16*)alloc((size_t)kNG * kH * 2);
  u16* w2h = (u16*)alloc((size_t)kNG * kH * 2);
  u16* w3i = (u16*)alloc((size_t)kNG * kH * 2);
  u16* w3h = (u16*)alloc((size_t)kNG * kH * 2);
  u16* wo  = (u16*)alloc((size_t)384 * kH * 2);
  u16* eb  = (u16*)alloc((size_t)kV * kE * 2);
  float* bi1 = (float*)alloc(kNG * 4);
  float* bh1 = (float*)alloc(kNG * 4);
  float* bi2 = (float*)alloc(kNG * 4);
  float* bh2 = (float*)alloc(kNG * 4);
  float* bi3 = (float*)alloc(kNG * 4);
  float* bh3 = (float*)alloc(kNG * 4);
  float* h1f = (float*)alloc((size_t)2 * kB * kH * 4);
  float* h2f = (float*)alloc((size_t)2 * kB * kH * 4);
  float* h3f = (float*)alloc((size_t)2 * kB * kH * 4);
  u16* h1b = (u16*)alloc((size_t)2 * kB * kH * 2);
  u16* h2b = (u16*)alloc((size_t)2 * kB * kH * 2);
  u16* h3b = (u16*)alloc((size_t)2 * kB * kH * 2);
  unsigned* bar = (unsigned*)alloc(4096);
  (void)ws_size; (void)in_sizes; (void)n_in; (void)out_size;

  k_conv_w<<<(kNG * kE + 255) / 256, 256, 0, stream>>>(w_ih1, w1i, kE, 9);
  k_conv_w<<<(kNG * kH + 255) / 256, 256, 0, stream>>>(w_hh1, w1h, kH, 10);
  k_conv_w<<<(kNG * kH + 255) / 256, 256, 0, stream>>>(w_ih2, w2i, kH, 10);
  k_conv_w<<<(kNG * kH + 255) / 256, 256, 0, stream>>>(w_hh2, w2h, kH, 10);
  k_conv_w<<<(kNG * kH + 255) / 256, 256, 0, stream>>>(w_ih3, w3i, kH, 10);
  k_conv_w<<<(kNG * kH + 255) / 256, 256, 0, stream>>>(w_hh3, w3h, kH, 10);
  k_conv_b<<<(kNG + 255) / 256, 256, 0, stream>>>(b_ih1, bi1);
  k_conv_b<<<(kNG + 255) / 256, 256, 0, stream>>>(b_hh1, bh1);
  k_conv_b<<<(kNG + 255) / 256, 256, 0, stream>>>(b_ih2, bi2);
  k_conv_b<<<(kNG + 255) / 256, 256, 0, stream>>>(b_hh2, bh2);
  k_conv_b<<<(kNG + 255) / 256, 256, 0, stream>>>(b_ih3, bi3);
  k_conv_b<<<(kNG + 255) / 256, 256, 0, stream>>>(b_hh3, bh3);
  k_conv_wout<<<(384 * kH + 255) / 256, 256, 0, stream>>>(w_out, wo);
  k_conv_emb<<<(kV * kE + 255) / 256, 256, 0, stream>>>(emb, eb);

  hipMemsetAsync(h1f, 0, (size_t)3 * 2 * kB * kH * 4, stream);  // h1f,h2f,h3f contiguous
  hipMemsetAsync(h1b, 0, (size_t)3 * 2 * kB * kH * 2, stream);  // h1b,h2b,h3b contiguous
  hipMemsetAsync(bar, 0, 4096, stream);
  hipMemsetAsync(d_out, 0, (size_t)kB * 4, stream);

  Params P;
  P.target = target; P.bosp = bosp; P.b_out = b_out;
  P.w1i = w1i; P.w1h = w1h; P.w2i = w2i; P.w2h = w2h; P.w3i = w3i; P.w3h = w3h;
  P.wout = wo; P.embb = eb;
  P.bi1 = bi1; P.bh1 = bh1; P.bi2 = bi2; P.bh2 = bh2; P.bi3 = bi3; P.bh3 = bh3;
  P.h1f = h1f; P.h2f = h2f; P.h3f = h3f;
  P.h1b = h1b; P.h2b = h2b; P.h3b = h3b;
  P.lp = (float*)d_out;
  P.acnt = bar; P.gflag = bar + 512;

  rnn_main<<<dim3(NB), dim3(256), 0, stream>>>(P);
}

// Round 6
// 4532.240 us; speedup vs baseline: 11.3222x; 1.8967x over previous
//
#include <hip/hip_runtime.h>
#include <hip/hip_bf16.h>
#include <cstdint>

// Problem constants
constexpr int kT = 128;    // sequence length
constexpr int kB = 256;    // batch
constexpr int kE = 512;    // embed dim
constexpr int kH = 1024;   // hidden
constexpr int kV = 348;    // vocab
constexpr int kNG = 3072;  // 3*H gate width
constexpr int NB = 208;    // 192 layer blocks + 16 E blocks (<=256 CUs, all resident)

constexpr float kScale = 32.f;        // fp8 storage scale (avoids e4m3 subnormal floor)
constexpr float kInvSS = 1.f / 1024.f; // 1/(kScale*kScale) applied to accumulators

typedef float f4v __attribute__((ext_vector_type(4)));   // MFMA accumulator
typedef unsigned short u16;
typedef unsigned char u8;

// float -> fp8 e4m3 (OCP) via HW packed convert; low byte of the pair
__device__ __forceinline__ u8 f2e4m3(float x) {
  int p = __builtin_amdgcn_cvt_pk_fp8_f32(x, x, 0, false);
  return (u8)(p & 0xff);
}

// device-coherent (cross-XCD) accessors: bypass L1/L2, hit MALL coherent point
__device__ __forceinline__ uint64_t ldv_u64(const void* p) {
  return __hip_atomic_load((const uint64_t*)p, __ATOMIC_RELAXED, __HIP_MEMORY_SCOPE_AGENT);
}
__device__ __forceinline__ void stv_u8(u8* p, u8 v) {
  __hip_atomic_store(p, v, __ATOMIC_RELAXED, __HIP_MEMORY_SCOPE_AGENT);
}

// gate-major n = gate*H + j  ->  interleaved col = 48*(j/16) + 16*gate + (j%16)
__device__ __forceinline__ int permn(int n) {
  int gate = n >> 10, j = n & 1023;
  return ((j >> 4) * 48) + gate * 16 + (j & 15);
}

struct Params {
  const int* target; const int* bosp; const float* b_out;
  const u8 *w1i, *w1h, *w2i, *w2h, *w3i, *w3h, *wout, *embb;  // fp8 x32
  const float *bi1, *bh1, *bi2, *bh2, *bi3, *bh3;
  float *h1f, *h2f, *h3f;       // [2][B][H] fp32 state (block-local, cached)
  u8    *h1b, *h2b, *h3b;       // [2][B][H] fp8 x32 state (cross-block, sc1)
  float *lp;                    // [B] output accumulator (= d_out)
  unsigned *acnt; unsigned *gflag;
};

union SMem {
  struct { u8 A[128 * 144]; u8 B[96 * 144]; } mm;  // 144B row stride (16B-aligned, balanced banks)
  float logits[16 * 400];
};

// ---- grid barrier: relaxed flag ops only, no cache-maintenance fences ----
__device__ __forceinline__ void gbar(unsigned* acnt, unsigned* gflag, unsigned s) {
  asm volatile("s_waitcnt vmcnt(0)" ::: "memory");
  __syncthreads();
  if (threadIdx.x == 0) {
    const unsigned g = blockIdx.x & 31u;
    __hip_atomic_fetch_add(&acnt[g * 16], 1u, __ATOMIC_RELAXED, __HIP_MEMORY_SCOPE_AGENT);
    if (blockIdx.x == 0) {
      for (;;) {
        unsigned sum = 0;
#pragma unroll
        for (int i = 0; i < 32; ++i)
          sum += __hip_atomic_load(&acnt[i * 16], __ATOMIC_RELAXED, __HIP_MEMORY_SCOPE_AGENT);
        if (sum >= (unsigned)NB * (s + 1u)) break;
        __builtin_amdgcn_s_sleep(4);
      }
#pragma unroll
      for (int i = 0; i < 32; ++i)
        __hip_atomic_store(&gflag[i * 16], s + 1u, __ATOMIC_RELAXED, __HIP_MEMORY_SCOPE_AGENT);
    } else {
      while (__hip_atomic_load(&gflag[g * 16], __ATOMIC_RELAXED, __HIP_MEMORY_SCOPE_AGENT) <= s)
        __builtin_amdgcn_s_sleep(8);
    }
    asm volatile("" ::: "memory");
  }
  __syncthreads();
}

// ---------------- one matmul phase: acc{R,Z,N} += A(128xK) @ W(96xK)^T, fp8, BK=128 ----------------
// 1-deep register prefetch. EMB: A gathered from fp8 embedding (cached); else sc1 h-state.
template<int K, bool EMB>
__device__ __forceinline__ void mm_phase(SMem& sm, const u8* __restrict__ Asrc,
    const u8* __restrict__ W, int b0, int n0,
    f4v* aR, f4v* aZ, f4v* aN,
    const int* __restrict__ target, int bos, int u)
{
  const int t = threadIdx.x, lane = t & 63, wv = t >> 6;
  const int wm = wv >> 1, wg = wv & 1, li = lane & 15, q = lane >> 4;
  uint64_t ra[4][2];
  uint4 rb[3];

  auto stage = [&](int k0) {
#pragma unroll
    for (int p = 0; p < 4; ++p) {                 // A: 128 rows x 128B, 16B chunks
      int id = p * 256 + t, r = id >> 3, c = id & 7;
      if (EMB) {
        int tok = (u == 0) ? bos : target[(b0 + r) * kT + (u - 1)];
        uint4 v = *(const uint4*)&Asrc[(size_t)tok * K + k0 + c * 16];
        ra[p][0] = ((uint64_t)v.y << 32) | v.x;
        ra[p][1] = ((uint64_t)v.w << 32) | v.z;
      } else {
        const u8* src = Asrc + (size_t)(b0 + r) * kH + k0 + c * 16;
        ra[p][0] = ldv_u64(src); ra[p][1] = ldv_u64(src + 8);
      }
    }
#pragma unroll
    for (int p = 0; p < 3; ++p) {                 // B: 96 weight rows (cached, L2-resident)
      int id = p * 256 + t, r = id >> 3, c = id & 7;
      rb[p] = *(const uint4*)&W[(size_t)(n0 + r) * K + k0 + c * 16];
    }
  };

  stage(0);
  for (int it = 0; it < K / 128; ++it) {
    __syncthreads();
#pragma unroll
    for (int p = 0; p < 4; ++p) {
      int id = p * 256 + t, r = id >> 3, c = id & 7;
      *(uint64_t*)&sm.mm.A[r * 144 + c * 16] = ra[p][0];
      *(uint64_t*)&sm.mm.A[r * 144 + c * 16 + 8] = ra[p][1];
    }
#pragma unroll
    for (int p = 0; p < 3; ++p) {
      int id = p * 256 + t, r = id >> 3, c = id & 7;
      *(uint4*)&sm.mm.B[r * 144 + c * 16] = rb[p];
    }
    __syncthreads();
    if (it + 1 < K / 128) stage((it + 1) * 128);  // prefetch overlaps MFMAs below
#pragma unroll
    for (int kk = 0; kk < 128; kk += 32) {
      int lk = kk + q * 8;
      long a[4], bb[3];
#pragma unroll
      for (int m2 = 0; m2 < 4; ++m2)
        a[m2] = *(const long*)&sm.mm.A[(64 * wm + 16 * m2 + li) * 144 + lk];
#pragma unroll
      for (int g = 0; g < 3; ++g)
        bb[g] = *(const long*)&sm.mm.B[(48 * wg + 16 * g + li) * 144 + lk];
#pragma unroll
      for (int m2 = 0; m2 < 4; ++m2) {
        aR[m2] = __builtin_amdgcn_mfma_f32_16x16x32_fp8_fp8(a[m2], bb[0], aR[m2], 0, 0, 0);
        aZ[m2] = __builtin_amdgcn_mfma_f32_16x16x32_fp8_fp8(a[m2], bb[1], aZ[m2], 0, 0, 0);
        aN[m2] = __builtin_amdgcn_mfma_f32_16x16x32_fp8_fp8(a[m2], bb[2], aN[m2], 0, 0, 0);
      }
    }
  }
}

// ---------------- merged layer stage: gi + gh + GRU update, tile 128b x 32j ----------------
template<int K1, bool L1>
__device__ void do_L(SMem& sm, const u8* __restrict__ xsrc,
                     const u8* __restrict__ hbPrev, const float* __restrict__ hfPrev,
                     const u8* __restrict__ Wih, const u8* __restrict__ Whh,
                     const float* __restrict__ biP, const float* __restrict__ bhP,
                     float* __restrict__ hfOut, u8* __restrict__ hbOut,
                     const int* __restrict__ target, int bos, int u, int mt, int jt)
{
  const int b0 = mt * 128, j0 = jt * 32, n0 = jt * 96;
  f4v aR[4], aZ[4], aNi[4], aNh[4];
#pragma unroll
  for (int i = 0; i < 4; ++i) {
    aR[i] = f4v{0.f,0.f,0.f,0.f}; aZ[i] = f4v{0.f,0.f,0.f,0.f};
    aNi[i] = f4v{0.f,0.f,0.f,0.f}; aNh[i] = f4v{0.f,0.f,0.f,0.f};
  }
  mm_phase<K1, L1>(sm, xsrc, Wih, b0, n0, aR, aZ, aNi, target, bos, u);      // gi
  mm_phase<kH, false>(sm, hbPrev, Whh, b0, n0, aR, aZ, aNh, target, bos, u); // gh

  const int t = threadIdx.x, lane = t & 63, wv = t >> 6;
  const int wm = wv >> 1, wg = wv & 1, li = lane & 15, q = lane >> 4;
  const int j = j0 + 16 * wg + li;
  const int cr = n0 + 48 * wg + li;
  const float bR = biP[cr] + bhP[cr];
  const float bZ = biP[cr + 16] + bhP[cr + 16];
  const float biN = biP[cr + 32], bhN = bhP[cr + 32];
  float hold[4][4];
#pragma unroll
  for (int m2 = 0; m2 < 4; ++m2)
#pragma unroll
    for (int r = 0; r < 4; ++r) {
      int b = b0 + 64 * wm + 16 * m2 + 4 * q + r;
      hold[m2][r] = hfPrev[(size_t)b * kH + j];  // block-local, cached
    }
#pragma unroll
  for (int m2 = 0; m2 < 4; ++m2)
#pragma unroll
    for (int r = 0; r < 4; ++r) {
      int b = b0 + 64 * wm + 16 * m2 + 4 * q + r;
      float rg = 1.f / (1.f + __expf(-(aR[m2][r] * kInvSS + bR)));
      float zg = 1.f / (1.f + __expf(-(aZ[m2][r] * kInvSS + bZ)));
      float np = (aNi[m2][r] * kInvSS + biN) + rg * (aNh[m2][r] * kInvSS + bhN);
      float nh = 2.f / (1.f + __expf(-2.f * np)) - 1.f;   // tanh
      float hnew = (1.f - zg) * nh + zg * hold[m2][r];
      hfOut[(size_t)b * kH + j] = hnew;                   // local fp32, cached
      stv_u8(&hbOut[(size_t)b * kH + j], f2e4m3(hnew * kScale));  // cross-block fp8, sc1
    }
}

// ---------------- E stage: logits + log_softmax + gather (16 rows/block) ----------------
__device__ void do_E(SMem& sm, const u8* __restrict__ h3b, const u8* __restrict__ wo,
                     const float* __restrict__ b_out, const int* __restrict__ target,
                     float* __restrict__ lp, int u, int tile)
{
  const int b0 = tile * 16;
  const int t = threadIdx.x, lane = t & 63, wv = t >> 6;
  const int li = lane & 15, q = lane >> 4;
  f4v acc[6];
#pragma unroll
  for (int f = 0; f < 6; ++f) acc[f] = f4v{0.f, 0.f, 0.f, 0.f};

  const u8* ap = h3b + (size_t)(b0 + li) * kH + q * 8;
  uint64_t aCur = ldv_u64(ap);
  uint64_t bCur[6], bNx[6];
#pragma unroll
  for (int f = 0; f < 6; ++f)
    bCur[f] = *(const uint64_t*)&wo[(size_t)(96 * wv + 16 * f + li) * kH + q * 8];
  for (int k0 = 0; k0 < kH; k0 += 32) {
    uint64_t aNx = 0;
    if (k0 + 32 < kH) {
      aNx = ldv_u64(ap + k0 + 32);
#pragma unroll
      for (int f = 0; f < 6; ++f)
        bNx[f] = *(const uint64_t*)&wo[(size_t)(96 * wv + 16 * f + li) * kH + k0 + 32 + q * 8];
    }
#pragma unroll
    for (int f = 0; f < 6; ++f)
      acc[f] = __builtin_amdgcn_mfma_f32_16x16x32_fp8_fp8((long)aCur, (long)bCur[f], acc[f], 0, 0, 0);
    aCur = aNx;
#pragma unroll
    for (int f = 0; f < 6; ++f) bCur[f] = bNx[f];
  }
#pragma unroll
  for (int f = 0; f < 6; ++f) {
    int n = 96 * wv + 16 * f + li;
    if (n < kV) {
      float bo = b_out[n];
#pragma unroll
      for (int r = 0; r < 4; ++r)
        sm.logits[(4 * q + r) * 400 + n] = acc[f][r] * kInvSS + bo;
    }
  }
  __syncthreads();
  int m = 4 * wv + q;
  int b = b0 + m;
  float mx = -1e30f;
  for (int cc = li; cc < kV; cc += 16) mx = fmaxf(mx, sm.logits[m * 400 + cc]);
#pragma unroll
  for (int d = 1; d < 16; d <<= 1) mx = fmaxf(mx, __shfl_xor(mx, d, 16));
  float se = 0.f;
  for (int cc = li; cc < kV; cc += 16) se += __expf(sm.logits[m * 400 + cc] - mx);
#pragma unroll
  for (int d = 1; d < 16; d <<= 1) se += __shfl_xor(se, d, 16);
  int tgt = target[b * kT + u];
  float logp = sm.logits[m * 400 + tgt] - mx - __logf(se);
  if (li == 0) lp[b] += logp;
}

// ---------------- main persistent kernel ----------------
__global__ __launch_bounds__(256, 1) void rnn_main(Params P)
{
  __shared__ SMem sm;
  const int bid = blockIdx.x;
  const int bos = P.bosp[0];
  const size_t HS = (size_t)kB * kH;

  // mt-pair sharing weights sits 8 bids apart (same XCD under bid%8 round-robin)
  const int local = bid & 63;
  const int mt = (local >> 3) & 1;
  const int jt = (local & 7) | ((local >> 4) << 3);

  for (int s = 0; s < kT + 3; ++s) {
    if (bid < 64) {                        // layer 1, u = s
      int u = s;
      if (u < kT)
        do_L<kE, true>(sm, P.embb,
                       P.h1b + (size_t)((u - 1) & 1) * HS, P.h1f + (size_t)((u - 1) & 1) * HS,
                       P.w1i, P.w1h, P.bi1, P.bh1,
                       P.h1f + (size_t)(u & 1) * HS, P.h1b + (size_t)(u & 1) * HS,
                       P.target, bos, u, mt, jt);
    } else if (bid < 128) {                // layer 2, u = s-1
      int u = s - 1;
      if (u >= 0 && u < kT)
        do_L<kH, false>(sm, P.h1b + (size_t)(u & 1) * HS,
                        P.h2b + (size_t)((u - 1) & 1) * HS, P.h2f + (size_t)((u - 1) & 1) * HS,
                        P.w2i, P.w2h, P.bi2, P.bh2,
                        P.h2f + (size_t)(u & 1) * HS, P.h2b + (size_t)(u & 1) * HS,
                        P.target, bos, u, mt, jt);
    } else if (bid < 192) {                // layer 3, u = s-2
      int u = s - 2;
      if (u >= 0 && u < kT)
        do_L<kH, false>(sm, P.h2b + (size_t)(u & 1) * HS,
                        P.h3b + (size_t)((u - 1) & 1) * HS, P.h3f + (size_t)((u - 1) & 1) * HS,
                        P.w3i, P.w3h, P.bi3, P.bh3,
                        P.h3f + (size_t)(u & 1) * HS, P.h3b + (size_t)(u & 1) * HS,
                        P.target, bos, u, mt, jt);
    } else {                               // E, u = s-3
      int u = s - 3;
      if (u >= 0 && u < kT)
        do_E(sm, P.h3b + (size_t)(u & 1) * HS, P.wout, P.b_out, P.target, P.lp, u, bid - 192);
    }
    gbar(P.acnt, P.gflag, (unsigned)s);
  }
}

// ---------------- conversion / init kernels (fp8 x32) ----------------
__global__ void k_conv_w(const float* __restrict__ w, u8* __restrict__ wp, int K, int logK) {
  int idx = blockIdx.x * 256 + threadIdx.x;
  if (idx >= kNG * K) return;
  int n = idx >> logK, k = idx & (K - 1);
  wp[(size_t)permn(n) * K + k] = f2e4m3(w[idx] * kScale);
}
__global__ void k_conv_b(const float* __restrict__ b, float* __restrict__ bp) {
  int idx = blockIdx.x * 256 + threadIdx.x;
  if (idx < kNG) bp[permn(idx)] = b[idx];
}
__global__ void k_conv_wout(const float* __restrict__ w, u8* __restrict__ wp) {
  int idx = blockIdx.x * 256 + threadIdx.x;
  if (idx >= 384 * kH) return;
  int n = idx >> 10, k = idx & 1023;
  wp[idx] = (n < kV) ? f2e4m3(w[(size_t)n * kH + k] * kScale) : (u8)0;
}
__global__ void k_conv_emb(const float* __restrict__ e, u8* __restrict__ ep) {
  int idx = blockIdx.x * 256 + threadIdx.x;
  if (idx < kV * kE) ep[idx] = f2e4m3(e[idx] * kScale);
}

extern "C" void kernel_launch(void* const* d_in, const int* in_sizes, int n_in,
                              void* d_out, int out_size, void* d_ws, size_t ws_size,
                              hipStream_t stream)
{
  const int*   target = (const int*)d_in[0];
  const int*   bosp   = (const int*)d_in[1];
  const float* emb    = (const float*)d_in[2];
  const float* w_ih1  = (const float*)d_in[3];
  const float* w_hh1  = (const float*)d_in[4];
  const float* b_ih1  = (const float*)d_in[5];
  const float* b_hh1  = (const float*)d_in[6];
  const float* w_ih2  = (const float*)d_in[7];
  const float* w_hh2  = (const float*)d_in[8];
  const float* b_ih2  = (const float*)d_in[9];
  const float* b_hh2  = (const float*)d_in[10];
  const float* w_ih3  = (const float*)d_in[11];
  const float* w_hh3  = (const float*)d_in[12];
  const float* b_ih3  = (const float*)d_in[13];
  const float* b_hh3  = (const float*)d_in[14];
  const float* w_out  = (const float*)d_in[15];
  const float* b_out  = (const float*)d_in[16];

  char* ws = (char*)d_ws;
  size_t off = 0;
  auto alloc = [&](size_t bytes) -> void* {
    void* p = ws + off;
    off = (off + bytes + 511) & ~(size_t)511;
    return p;
  };
  u8* w1i = (u8*)alloc((size_t)kNG * kE);
  u8* w1h = (u8*)alloc((size_t)kNG * kH);
  u8* w2i = (u8*)alloc((size_t)kNG * kH);
  u8* w2h = (u8*)alloc((size_t)kNG * kH);
  u8* w3i = (u8*)alloc((size_t)kNG * kH);
  u8* w3h = (u8*)alloc((size_t)kNG * kH);
  u8* wo  = (u8*)alloc((size_t)384 * kH);
  u8* eb  = (u8*)alloc((size_t)kV * kE);
  float* bi1 = (float*)alloc(kNG * 4);
  float* bh1 = (float*)alloc(kNG * 4);
  float* bi2 = (float*)alloc(kNG * 4);
  float* bh2 = (float*)alloc(kNG * 4);
  float* bi3 = (float*)alloc(kNG * 4);
  float* bh3 = (float*)alloc(kNG * 4);
  float* h1f = (float*)alloc((size_t)2 * kB * kH * 4);
  float* h2f = (float*)alloc((size_t)2 * kB * kH * 4);
  float* h3f = (float*)alloc((size_t)2 * kB * kH * 4);
  u8* h1b = (u8*)alloc((size_t)2 * kB * kH);
  u8* h2b = (u8*)alloc((size_t)2 * kB * kH);
  u8* h3b = (u8*)alloc((size_t)2 * kB * kH);
  unsigned* bar = (unsigned*)alloc(4096);
  (void)ws_size; (void)in_sizes; (void)n_in; (void)out_size;

  k_conv_w<<<(kNG * kE + 255) / 256, 256, 0, stream>>>(w_ih1, w1i, kE, 9);
  k_conv_w<<<(kNG * kH + 255) / 256, 256, 0, stream>>>(w_hh1, w1h, kH, 10);
  k_conv_w<<<(kNG * kH + 255) / 256, 256, 0, stream>>>(w_ih2, w2i, kH, 10);
  k_conv_w<<<(kNG * kH + 255) / 256, 256, 0, stream>>>(w_hh2, w2h, kH, 10);
  k_conv_w<<<(kNG * kH + 255) / 256, 256, 0, stream>>>(w_ih3, w3i, kH, 10);
  k_conv_w<<<(kNG * kH + 255) / 256, 256, 0, stream>>>(w_hh3, w3h, kH, 10);
  k_conv_b<<<(kNG + 255) / 256, 256, 0, stream>>>(b_ih1, bi1);
  k_conv_b<<<(kNG + 255) / 256, 256, 0, stream>>>(b_hh1, bh1);
  k_conv_b<<<(kNG + 255) / 256, 256, 0, stream>>>(b_ih2, bi2);
  k_conv_b<<<(kNG + 255) / 256, 256, 0, stream>>>(b_hh2, bh2);
  k_conv_b<<<(kNG + 255) / 256, 256, 0, stream>>>(b_ih3, bi3);
  k_conv_b<<<(kNG + 255) / 256, 256, 0, stream>>>(b_hh3, bh3);
  k_conv_wout<<<(384 * kH + 255) / 256, 256, 0, stream>>>(w_out, wo);
  k_conv_emb<<<(kV * kE + 255) / 256, 256, 0, stream>>>(emb, eb);

  hipMemsetAsync(h1f, 0, (size_t)3 * 2 * kB * kH * 4, stream);  // h1f,h2f,h3f contiguous
  hipMemsetAsync(h1b, 0, (size_t)3 * 2 * kB * kH, stream);      // h1b,h2b,h3b contiguous
  hipMemsetAsync(bar, 0, 4096, stream);
  hipMemsetAsync(d_out, 0, (size_t)kB * 4, stream);

  Params P;
  P.target = target; P.bosp = bosp; P.b_out = b_out;
  P.w1i = w1i; P.w1h = w1h; P.w2i = w2i; P.w2h = w2h; P.w3i = w3i; P.w3h = w3h;
  P.wout = wo; P.embb = eb;
  P.bi1 = bi1; P.bh1 = bh1; P.bi2 = bi2; P.bh2 = bh2; P.bi3 = bi3; P.bh3 = bh3;
  P.h1f = h1f; P.h2f = h2f; P.h3f = h3f;
  P.h1b = h1b; P.h2b = h2b; P.h3b = h3b;
  P.lp = (float*)d_out;
  P.acnt = bar; P.gflag = bar + 512;

  rnn_main<<<dim3(NB), dim3(256), 0, stream>>>(P);
}